// Round 14
// baseline (1021.375 us; speedup 1.0000x reference)
//
#include <hip/hip_runtime.h>
#include <math.h>

#define N_NODES 100000
#define N_EDGES 1600000
#define EP (N_EDGES + N_NODES)   // edges + self-loops = 1,700,000
#define NH 8
#define NC 64
#define NG 64
#define HC 512
#define SCAN_BLOCKS ((N_NODES + 255) / 256)   // 391
#define NPART 32                              // pooling atomic partitions
#define BPSTR 80                              // fp8 epilogue patch row stride (bytes, 16B-aligned)

typedef unsigned short bf16_t;
typedef unsigned char fp8_t;
typedef __attribute__((ext_vector_type(8))) short short8;
typedef __attribute__((ext_vector_type(4))) float floatx4;
typedef __attribute__((ext_vector_type(2))) float floatx2;

__device__ inline bf16_t f2bf(float f) {
    union { float f; unsigned int i; } x;
    x.f = f;
    unsigned int b = x.i;
    return (bf16_t)((b + 0x7fffu + ((b >> 16) & 1u)) >> 16);
}
__device__ inline fp8_t f2fp8(float f) {   // OCP e4m3fn, RNE, HW saturate
    int v = __builtin_amdgcn_cvt_pk_fp8_f32(f, f, 0, false);
    return (fp8_t)v;
}

// async global->LDS, 16B per lane; lds base must be wave-uniform (HW: base + lane*16)
__device__ inline void ldsload16(const void* g, void* l) {
    __builtin_amdgcn_global_load_lds(
        (const __attribute__((address_space(1))) unsigned int*)g,
        (__attribute__((address_space(3))) unsigned int*)l, 16, 0, 0);
}

// ---------------- prep (block NBW2T) + W2 transpose/bf16 (blocks 0..NBW2T-1) ----------------
#define NBW2T (HC * HC / 256)   // 1024
__global__ void k_prepw2t(const float* __restrict__ W1, const float* __restrict__ a1s,
                          const float* __restrict__ a1d, float* __restrict__ wprep,
                          const float* __restrict__ W2, bf16_t* __restrict__ W2T) {
    if (blockIdx.x == NBW2T) {
        int t = threadIdx.x;
        if (t < 48) {
            int isD = t >= 24;
            int tt = t % 24;
            int h = tt / 3, k = tt % 3;
            const float* a = isD ? a1d : a1s;
            float s = 0.f;
            for (int c = 0; c < 64; c++) s += W1[k * HC + h * 64 + c] * a[h * 64 + c];
            wprep[t] = s;
        }
        return;
    }
    int i = blockIdx.x * 256 + threadIdx.x;
    int n = i >> 9, kp = i & 511;
    int k = (kp & 7) * 64 + (kp >> 3);
    W2T[i] = f2bf(W2[k * HC + n]);
}

// ---------------- CSR build ----------------
__global__ void k_deg(const int* __restrict__ ei, int* __restrict__ deg) {
    int i = blockIdx.x * 256 + threadIdx.x;
    if (i >= EP) return;
    int d = (i < N_EDGES) ? ei[N_EDGES + i] : (i - N_EDGES);
    atomicAdd(&deg[d], 1);
}

__global__ void k_scan1(const int* __restrict__ deg, int* __restrict__ rowptr, int* __restrict__ part) {
    __shared__ int s[256];
    int t = threadIdx.x, i = blockIdx.x * 256 + t;
    int v = (i < N_NODES) ? deg[i] : 0;
    s[t] = v;
    __syncthreads();
    for (int off = 1; off < 256; off <<= 1) {
        int u = (t >= off) ? s[t - off] : 0;
        __syncthreads();
        s[t] += u;
        __syncthreads();
    }
    if (i < N_NODES) rowptr[i] = s[t] - v;
    if (t == 255) part[blockIdx.x] = s[t];
}

__global__ void k_scan2(int* __restrict__ part, int* __restrict__ rowptr, int* __restrict__ gstart) {
    __shared__ int s[512];
    int t = threadIdx.x;
    int v = (t < SCAN_BLOCKS) ? part[t] : 0;
    s[t] = v;
    __syncthreads();
    for (int off = 1; off < 512; off <<= 1) {
        int u = (t >= off) ? s[t - off] : 0;
        __syncthreads();
        s[t] += u;
        __syncthreads();
    }
    part[t] = s[t] - v;
    if (t == 0) rowptr[N_NODES] = EP;
    if (t <= NG) gstart[t] = N_NODES;   // fused init for graph bounds
}

// scan3 + cursor init + x padding + graph bounds, all fused
__global__ void k_scan3(const int* __restrict__ part, int* __restrict__ rowptr,
                        int* __restrict__ cursor, const float* __restrict__ x,
                        float* __restrict__ xp, const int* __restrict__ batch,
                        int* __restrict__ gstart) {
    int i = blockIdx.x * 256 + threadIdx.x;
    if (i < N_NODES) {
        int v = rowptr[i] + part[blockIdx.x];
        rowptr[i] = v;
        cursor[i] = v;
        xp[i * 4 + 0] = x[i * 3 + 0];
        xp[i * 4 + 1] = x[i * 3 + 1];
        xp[i * 4 + 2] = x[i * 3 + 2];
        xp[i * 4 + 3] = 0.f;
        int b = batch[i];
        if (i == 0) {
            for (int g = 0; g <= b; g++) gstart[g] = 0;
        } else {
            int bp = batch[i - 1];
            if (b != bp)
                for (int g = bp + 1; g <= b; g++) gstart[g] = i;
        }
    }
}

__global__ void k_scatter(const int* __restrict__ ei, int* __restrict__ cursor, int* __restrict__ csr) {
    int i = blockIdx.x * 256 + threadIdx.x;
    if (i >= EP) return;
    int s, d;
    if (i < N_EDGES) { s = ei[i]; d = ei[N_EDGES + i]; }
    else { s = i - N_EDGES; d = s; }
    int pos = atomicAdd(&cursor[d], 1);
    csr[pos] = s;
}

// ---------------- layer 1: 32 lanes per dst (2 dsts/wave) ----------------
__global__ __launch_bounds__(256) void k_layer1(
    const float* __restrict__ xp, const int* __restrict__ rowptr, const int* __restrict__ csr,
    const float* __restrict__ W1, const float* __restrict__ wprep, const float* __restrict__ b1,
    bf16_t* __restrict__ x1p) {
    __shared__ float w1s[1536];
    __shared__ float wp[48];
    int tid = threadIdx.x;
    for (int i = tid; i < 1536; i += 256) w1s[i] = W1[i];
    if (tid < 48) wp[tid] = wprep[tid];
    __syncthreads();
    int lane = tid & 63, wave = tid >> 6;
    int half = lane >> 5, l32 = lane & 31;
    int dst = blockIdx.x * 8 + wave * 2 + half;
    int rs = rowptr[dst], re = rowptr[dst + 1];
    float4 xd = *(const float4*)&xp[dst * 4];
    float ald[NH];
#pragma unroll
    for (int h = 0; h < NH; h++)
        ald[h] = xd.x * wp[24 + h * 3] + xd.y * wp[24 + h * 3 + 1] + xd.z * wp[24 + h * 3 + 2];
    float den[NH], c0[NH], c1[NH], c2[NH];
#pragma unroll
    for (int h = 0; h < NH; h++) { den[h] = 0.f; c0[h] = 0.f; c1[h] = 0.f; c2[h] = 0.f; }
    for (int base = rs; base < re; base += 32) {
        int e = base + l32;
        if (e < re) {
            int s = csr[e];
            float4 sv = *(const float4*)&xp[s * 4];
#pragma unroll
            for (int h = 0; h < NH; h++) {
                float ev = sv.x * wp[h * 3] + sv.y * wp[h * 3 + 1] + sv.z * wp[h * 3 + 2] + ald[h];
                ev = fmaxf(ev, 0.2f * ev);
                float w = __expf(ev);
                den[h] += w;
                c0[h] += w * sv.x;
                c1[h] += w * sv.y;
                c2[h] += w * sv.z;
            }
        }
    }
#pragma unroll
    for (int h = 0; h < NH; h++) {
#pragma unroll
        for (int off = 1; off < 32; off <<= 1) {
            den[h] += __shfl_xor(den[h], off, 64);
            c0[h] += __shfl_xor(c0[h], off, 64);
            c1[h] += __shfl_xor(c1[h], off, 64);
            c2[h] += __shfl_xor(c2[h], off, 64);
        }
    }
    bf16_t vbA[NH], vbB[NH];
#pragma unroll
    for (int h = 0; h < NH; h++) {
        int colA = h * 64 + l32;
        float vA = c0[h] * w1s[colA] + c1[h] * w1s[512 + colA] + c2[h] * w1s[1024 + colA];
        vA = vA / den[h] + b1[colA];
        vA = vA > 0.f ? vA : (__expf(vA) - 1.f);
        vbA[h] = f2bf(vA);
        int colB = colA + 32;
        float vB = c0[h] * w1s[colB] + c1[h] * w1s[512 + colB] + c2[h] * w1s[1024 + colB];
        vB = vB / den[h] + b1[colB];
        vB = vB > 0.f ? vB : (__expf(vB) - 1.f);
        vbB[h] = f2bf(vB);
    }
    uint4 oA, oB;
    oA.x = (unsigned int)vbA[0] | ((unsigned int)vbA[1] << 16);
    oA.y = (unsigned int)vbA[2] | ((unsigned int)vbA[3] << 16);
    oA.z = (unsigned int)vbA[4] | ((unsigned int)vbA[5] << 16);
    oA.w = (unsigned int)vbA[6] | ((unsigned int)vbA[7] << 16);
    oB.x = (unsigned int)vbB[0] | ((unsigned int)vbB[1] << 16);
    oB.y = (unsigned int)vbB[2] | ((unsigned int)vbB[3] << 16);
    oB.z = (unsigned int)vbB[4] | ((unsigned int)vbB[5] << 16);
    oB.w = (unsigned int)vbB[6] | ((unsigned int)vbB[7] << 16);
    *(uint4*)&x1p[(size_t)dst * HC + l32 * 8] = oA;
    *(uint4*)&x1p[(size_t)dst * HC + (l32 + 32) * 8] = oB;
}

// ---------------- GEMM2 128x128, BK=64, async staging; h2 OUTPUT IN FP8-e4m3 ----------------
__global__ __launch_bounds__(256) void k_gemm2(const bf16_t* __restrict__ A,
                                               const bf16_t* __restrict__ BT,
                                               fp8_t* __restrict__ Out,
                                               int row_base, int nrows,
                                               const float* __restrict__ a2s,
                                               const float* __restrict__ a2d,
                                               float* __restrict__ al2s,
                                               float* __restrict__ al2d) {
    __shared__ short smem[16384];          // As 8192 | Bs 8192 (128 rows x 64 shorts each)
    short* As = smem;
    short* Bs = smem + 8192;
    int tid = threadIdx.x;
    int lane = tid & 63, wave = tid >> 6;
    int wm = wave & 1, wn = wave >> 1;
    int lm = lane & 15, quad = lane >> 4;
    int gx = blockIdx.x, gy = blockIdx.y;
    int l8 = lane >> 3, lc8 = lane & 7;
    int sw = lc8 ^ l8;                     // swizzled global chunk for this lane
    const bf16_t* ga[4];
    const bf16_t* gb[4];
    short* la[4];
    short* lb[4];
#pragma unroll
    for (int it = 0; it < 4; it++) {
        int ar = gy * 128 + wave * 32 + it * 8 + l8;
        int arc = (ar < nrows) ? ar : 0;   // clamp OOB (rows never stored)
        ga[it] = A + (size_t)(row_base + arc) * HC + sw * 8;
        gb[it] = BT + (size_t)(gx * 128 + wave * 32 + it * 8 + l8) * HC + sw * 8;
        la[it] = As + (wave * 32 + it * 8) * 64;
        lb[it] = Bs + (wave * 32 + it * 8) * 64;
    }

    floatx4 acc[4][4];
#pragma unroll
    for (int mi = 0; mi < 4; mi++)
#pragma unroll
        for (int ni = 0; ni < 4; ni++) acc[mi][ni] = (floatx4){0.f, 0.f, 0.f, 0.f};

    int lmw = lm & 7;  // read-side swizzle key (row & 7)
    for (int k0 = 0; k0 < HC; k0 += 64) {
        __syncthreads();
#pragma unroll
        for (int it = 0; it < 4; it++) ldsload16(ga[it] + k0, la[it]);
#pragma unroll
        for (int it = 0; it < 4; it++) ldsload16(gb[it] + k0, lb[it]);
        __syncthreads();
        short8 af[4][2], bf[4][2];
#pragma unroll
        for (int mi = 0; mi < 4; mi++)
#pragma unroll
            for (int kk = 0; kk < 2; kk++) {
                int pos = (kk * 4 + quad) ^ lmw;
                af[mi][kk] = *(const short8*)&As[(wm * 64 + mi * 16 + lm) * 64 + pos * 8];
            }
#pragma unroll
        for (int ni = 0; ni < 4; ni++)
#pragma unroll
            for (int kk = 0; kk < 2; kk++) {
                int pos = (kk * 4 + quad) ^ lmw;
                bf[ni][kk] = *(const short8*)&Bs[(wn * 64 + ni * 16 + lm) * 64 + pos * 8];
            }
#pragma unroll
        for (int mi = 0; mi < 4; mi++)
#pragma unroll
            for (int ni = 0; ni < 4; ni++) {
                acc[mi][ni] = __builtin_amdgcn_mfma_f32_16x16x32_bf16(af[mi][0], bf[ni][0], acc[mi][ni], 0, 0, 0);
                acc[mi][ni] = __builtin_amdgcn_mfma_f32_16x16x32_bf16(af[mi][1], bf[ni][1], acc[mi][ni], 0, 0, 0);
            }
    }
    // ---- fused al2 from fp32 acc (EXACT logits; unaffected by fp8 h2 storage) ----
    int head = gx * 2 + wn;
    float a2sv[4], a2dv[4];
#pragma unroll
    for (int ni = 0; ni < 4; ni++) {
        int col = gx * 128 + wn * 64 + ni * 16 + lm;
        a2sv[ni] = a2s[col];
        a2dv[ni] = a2d[col];
    }
#pragma unroll
    for (int mi = 0; mi < 4; mi++) {
#pragma unroll
        for (int rg = 0; rg < 4; rg++) {
            int lrow = gy * 128 + wm * 64 + mi * 16 + quad * 4 + rg;
            float ps = 0.f, pd = 0.f;
#pragma unroll
            for (int ni = 0; ni < 4; ni++) {
                float v = acc[mi][ni][rg];
                ps += v * a2sv[ni];
                pd += v * a2dv[ni];
            }
#pragma unroll
            for (int off = 1; off < 16; off <<= 1) {
                ps += __shfl_xor(ps, off, 64);
                pd += __shfl_xor(pd, off, 64);
            }
            if (lrow < nrows && lm == 0) {
                int ar = row_base + lrow;
                al2s[ar * NH + head] = ps;
                al2d[ar * NH + head] = pd;
            }
        }
    }
    // ---- fp8 store via per-wave LDS byte patch (uint4 global stores, 64B/row segments) ----
    __syncthreads();
    unsigned char* bpatch = (unsigned char*)smem + wave * (32 * BPSTR);
#pragma unroll
    for (int p = 0; p < 2; p++) {
#pragma unroll
        for (int mih = 0; mih < 2; mih++) {
            int mi = p * 2 + mih;
#pragma unroll
            for (int ni = 0; ni < 4; ni++)
#pragma unroll
                for (int rg = 0; rg < 4; rg++) {
                    int rl = mih * 16 + quad * 4 + rg;
                    bpatch[rl * BPSTR + ni * 16 + lm] = f2fp8(acc[mi][ni][rg]);
                }
        }
        // same-wave LDS write->read in program order
#pragma unroll
        for (int it = 0; it < 2; it++) {
            int idx = it * 64 + lane;
            int rl = idx >> 2, c16 = idx & 3;
            uint4 v = *(uint4*)&bpatch[rl * BPSTR + c16 * 16];
            int lrow = gy * 128 + wm * 64 + p * 32 + rl;
            if (lrow < nrows)
                *(uint4*)&Out[(size_t)lrow * HC + wn * 64 + gx * 128 + c16 * 16] = v;
        }
        __syncthreads();
    }
}

// ---------------- layer 2: 2 dsts per wave (32 lanes each), fp8 gathers, fused pool --------
// lane l32 covers channels l32*16..+15 (one 16-chan slice of head hme=l32>>2); per edge it
// loads one uint4 (full row across the half-wave). Two independent dst chains per wave.
__global__ __launch_bounds__(256) void k_layer2pool(
    const fp8_t* __restrict__ h2lo, const fp8_t* __restrict__ h2hi, int srows,
    const float* __restrict__ al2s, const float* __restrict__ al2d,
    const int* __restrict__ rowptr, const int* __restrict__ csr, const float* __restrict__ b2,
    const int* __restrict__ batch, float* __restrict__ poolpart) {
    __shared__ float wlds[4][2][256];    // per wave/half: 32 edges x 8 head-weights
    __shared__ int   slds[4][2][32];
    __shared__ float vstage[4][2][512];  // post-ELU staging for coalesced atomics
    int tid = threadIdx.x, lane = tid & 63, wave = tid >> 6;
    int half = lane >> 5, l32 = lane & 31;
    int hme = l32 >> 2;
    int dst = blockIdx.x * 8 + wave * 2 + half;
    int rs = rowptr[dst], re = rowptr[dst + 1];
    float4 d0 = *(const float4*)&al2d[dst * NH];
    float4 d1 = *(const float4*)&al2d[dst * NH + 4];
    float ald[NH] = {d0.x, d0.y, d0.z, d0.w, d1.x, d1.y, d1.z, d1.w};
    float den[NH], acc[16];
#pragma unroll
    for (int h = 0; h < NH; h++) den[h] = 0.f;
#pragma unroll
    for (int q = 0; q < 16; q++) acc[q] = 0.f;
    for (int base = rs; base < re; base += 32) {
        int e = base + l32;
        int cl = re - base; if (cl > 32) cl = 32;
        float w[NH];
        int s = 0;
        if (e < re) {
            s = csr[e];
            float4 p0 = *(const float4*)&al2s[s * NH];
            float4 p1 = *(const float4*)&al2s[s * NH + 4];
            float als[NH] = {p0.x, p0.y, p0.z, p0.w, p1.x, p1.y, p1.z, p1.w};
#pragma unroll
            for (int h = 0; h < NH; h++) {
                float ev = als[h] + ald[h];
                ev = fmaxf(ev, 0.2f * ev);
                w[h] = __expf(ev);
                den[h] += w[h];
            }
        } else {
#pragma unroll
            for (int h = 0; h < NH; h++) w[h] = 0.f;
        }
        slds[wave][half][l32] = s;
        *(float4*)&wlds[wave][half][l32 * 8] = make_float4(w[0], w[1], w[2], w[3]);
        *(float4*)&wlds[wave][half][l32 * 8 + 4] = make_float4(w[4], w[5], w[6], w[7]);
        // same-wave LDS write->read in program order
        int j = 0;
        for (; j + 1 < cl; j += 2) {
            int s0 = slds[wave][half][j], s1 = slds[wave][half][j + 1];
            float w0 = wlds[wave][half][j * 8 + hme];
            float w1 = wlds[wave][half][(j + 1) * 8 + hme];
            const fp8_t* b0 = (s0 < srows) ? (h2lo + (size_t)s0 * HC) : (h2hi + (size_t)(s0 - srows) * HC);
            const fp8_t* b1p = (s1 < srows) ? (h2lo + (size_t)s1 * HC) : (h2hi + (size_t)(s1 - srows) * HC);
            uint4 v0 = *(const uint4*)&b0[l32 * 16];
            uint4 v1 = *(const uint4*)&b1p[l32 * 16];
            floatx2 c;
            c = __builtin_amdgcn_cvt_pk_f32_fp8(v0.x, false); acc[0] += w0 * c.x;  acc[1] += w0 * c.y;
            c = __builtin_amdgcn_cvt_pk_f32_fp8(v0.x, true);  acc[2] += w0 * c.x;  acc[3] += w0 * c.y;
            c = __builtin_amdgcn_cvt_pk_f32_fp8(v0.y, false); acc[4] += w0 * c.x;  acc[5] += w0 * c.y;
            c = __builtin_amdgcn_cvt_pk_f32_fp8(v0.y, true);  acc[6] += w0 * c.x;  acc[7] += w0 * c.y;
            c = __builtin_amdgcn_cvt_pk_f32_fp8(v0.z, false); acc[8] += w0 * c.x;  acc[9] += w0 * c.y;
            c = __builtin_amdgcn_cvt_pk_f32_fp8(v0.z, true);  acc[10] += w0 * c.x; acc[11] += w0 * c.y;
            c = __builtin_amdgcn_cvt_pk_f32_fp8(v0.w, false); acc[12] += w0 * c.x; acc[13] += w0 * c.y;
            c = __builtin_amdgcn_cvt_pk_f32_fp8(v0.w, true);  acc[14] += w0 * c.x; acc[15] += w0 * c.y;
            c = __builtin_amdgcn_cvt_pk_f32_fp8(v1.x, false); acc[0] += w1 * c.x;  acc[1] += w1 * c.y;
            c = __builtin_amdgcn_cvt_pk_f32_fp8(v1.x, true);  acc[2] += w1 * c.x;  acc[3] += w1 * c.y;
            c = __builtin_amdgcn_cvt_pk_f32_fp8(v1.y, false); acc[4] += w1 * c.x;  acc[5] += w1 * c.y;
            c = __builtin_amdgcn_cvt_pk_f32_fp8(v1.y, true);  acc[6] += w1 * c.x;  acc[7] += w1 * c.y;
            c = __builtin_amdgcn_cvt_pk_f32_fp8(v1.z, false); acc[8] += w1 * c.x;  acc[9] += w1 * c.y;
            c = __builtin_amdgcn_cvt_pk_f32_fp8(v1.z, true);  acc[10] += w1 * c.x; acc[11] += w1 * c.y;
            c = __builtin_amdgcn_cvt_pk_f32_fp8(v1.w, false); acc[12] += w1 * c.x; acc[13] += w1 * c.y;
            c = __builtin_amdgcn_cvt_pk_f32_fp8(v1.w, true);  acc[14] += w1 * c.x; acc[15] += w1 * c.y;
        }
        if (j < cl) {
            int sA = slds[wave][half][j];
            float wA = wlds[wave][half][j * 8 + hme];
            const fp8_t* bA = (sA < srows) ? (h2lo + (size_t)sA * HC) : (h2hi + (size_t)(sA - srows) * HC);
            uint4 vA = *(const uint4*)&bA[l32 * 16];
            floatx2 c;
            c = __builtin_amdgcn_cvt_pk_f32_fp8(vA.x, false); acc[0] += wA * c.x;  acc[1] += wA * c.y;
            c = __builtin_amdgcn_cvt_pk_f32_fp8(vA.x, true);  acc[2] += wA * c.x;  acc[3] += wA * c.y;
            c = __builtin_amdgcn_cvt_pk_f32_fp8(vA.y, false); acc[4] += wA * c.x;  acc[5] += wA * c.y;
            c = __builtin_amdgcn_cvt_pk_f32_fp8(vA.y, true);  acc[6] += wA * c.x;  acc[7] += wA * c.y;
            c = __builtin_amdgcn_cvt_pk_f32_fp8(vA.z, false); acc[8] += wA * c.x;  acc[9] += wA * c.y;
            c = __builtin_amdgcn_cvt_pk_f32_fp8(vA.z, true);  acc[10] += wA * c.x; acc[11] += wA * c.y;
            c = __builtin_amdgcn_cvt_pk_f32_fp8(vA.w, false); acc[12] += wA * c.x; acc[13] += wA * c.y;
            c = __builtin_amdgcn_cvt_pk_f32_fp8(vA.w, true);  acc[14] += wA * c.x; acc[15] += wA * c.y;
        }
    }
    // den reduction within each 32-lane half
#pragma unroll
    for (int h = 0; h < NH; h++)
#pragma unroll
        for (int off = 1; off < 32; off <<= 1) den[h] += __shfl_xor(den[h], off, 64);
    float dd = den[0];
#pragma unroll
    for (int h = 1; h < NH; h++) dd = (hme == h) ? den[h] : dd;
    float dinv = 1.0f / dd;
    // bias for channels l32*16 .. +15
    float bv[16];
#pragma unroll
    for (int q4 = 0; q4 < 4; q4++) {
        float4 b4 = *(const float4*)&b2[l32 * 16 + q4 * 4];
        bv[q4 * 4 + 0] = b4.x; bv[q4 * 4 + 1] = b4.y; bv[q4 * 4 + 2] = b4.z; bv[q4 * 4 + 3] = b4.w;
    }
#pragma unroll
    for (int q = 0; q < 16; q++) {
        float v = acc[q] * dinv + bv[q];
        v = v > 0.f ? v : (__expf(v) - 1.f);
        vstage[wave][half][l32 * 16 + q] = v;
    }
    int g = batch[dst];
    float* pp = poolpart + ((size_t)(blockIdx.x & (NPART - 1)) * NG + g) * HC;
    // coalesced atomics: 32 lanes cover 128B contiguous per instruction
#pragma unroll
    for (int h = 0; h < NH; h++) {
        atomicAdd(&pp[h * 64 + l32], vstage[wave][half][h * 64 + l32]);
        atomicAdd(&pp[h * 64 + 32 + l32], vstage[wave][half][h * 64 + 32 + l32]);
    }
}

// ---------------- fused pool-reduce + classifier ----------------
__global__ __launch_bounds__(256) void k_poolcls(const float* __restrict__ poolpart,
                                                 const int* __restrict__ gstart,
                                                 const float* __restrict__ Wc,
                                                 const float* __restrict__ bc,
                                                 float* __restrict__ out) {
    __shared__ float pl[512];
    int g = blockIdx.x, t = threadIdx.x;
    for (int c = t; c < HC; c += 256) {
        float s = 0.f;
        for (int p = 0; p < NPART; p++) s += poolpart[(size_t)p * NG * HC + g * HC + c];
        pl[c] = s;
    }
    __syncthreads();
    if (t < 10) {
        float cnt = fmaxf((float)(gstart[g + 1] - gstart[g]), 1.0f);
        float acc = 0.f;
        for (int k = 0; k < HC; k++) acc += pl[k] * Wc[k * 10 + t];
        out[g * 10 + t] = acc / cnt + bc[t];
    }
}

extern "C" void kernel_launch(void* const* d_in, const int* in_sizes, int n_in,
                              void* d_out, int out_size, void* d_ws, size_t ws_size,
                              hipStream_t stream) {
    const float* x   = (const float*)d_in[0];
    const int*   ei  = (const int*)d_in[1];
    const int*   bat = (const int*)d_in[2];
    const float* W1  = (const float*)d_in[3];
    const float* a1s = (const float*)d_in[4];
    const float* a1d = (const float*)d_in[5];
    const float* b1  = (const float*)d_in[6];
    const float* W2  = (const float*)d_in[7];
    const float* a2s = (const float*)d_in[8];
    const float* a2d = (const float*)d_in[9];
    const float* b2  = (const float*)d_in[10];
    const float* Wc  = (const float*)d_in[11];
    const float* bc  = (const float*)d_in[12];
    float* out = (float*)d_out;

    char* ws = (char*)d_ws;
    size_t off = 0;
    auto alloc = [&](size_t bytes) {
        size_t o = off;
        off += (bytes + 255) & ~(size_t)255;
        return o;
    };
    float*  wprep    = (float*)(ws + alloc(48 * 4));
    int*    rowptr   = (int*)(ws + alloc((size_t)(N_NODES + 1) * 4));
    int*    deg      = (int*)(ws + alloc((size_t)N_NODES * 4));
    int*    cursor   = (int*)(ws + alloc((size_t)N_NODES * 4));
    int*    part     = (int*)(ws + alloc(512 * 4));
    int*    gstart   = (int*)(ws + alloc(65 * 4));
    float*  xp       = (float*)(ws + alloc((size_t)N_NODES * 4 * 4));
    int*    csr      = (int*)(ws + alloc((size_t)EP * 4));
    bf16_t* x1b      = (bf16_t*)(ws + alloc((size_t)N_NODES * HC * 2));
    float*  al2s     = (float*)(ws + alloc((size_t)N_NODES * NH * 4));
    float*  al2d     = (float*)(ws + alloc((size_t)N_NODES * NH * 4));
    float*  poolpart = (float*)(ws + alloc((size_t)NPART * NG * HC * 4));
    // W2T (512KB) aliases deg+cursor (800KB, dead after k_scatter)
    bf16_t* W2T = (bf16_t*)deg;

    // slice tier: h2 is FP8 (1 byte/elem) — largest slice temp that fits
    size_t rem = (ws_size > off) ? ws_size - off : 0;
    int nslices, srows;
    if (rem >= (size_t)N_NODES * HC)      { nslices = 1;  srows = N_NODES; }
    else if (rem >= (size_t)50000 * HC)   { nslices = 2;  srows = 50000; }
    else if (rem >= (size_t)25000 * HC)   { nslices = 4;  srows = 25000; }
    else if (rem >= (size_t)12500 * HC)   { nslices = 8;  srows = 12500; }
    else                                  { nslices = 16; srows = 6250; }
    fp8_t* T = (fp8_t*)(ws + alloc((size_t)srows * HC));
    fp8_t* h2hi = (fp8_t*)x1b;   // shift-by-one in-place region (byte-indexed)

    hipMemsetAsync(deg, 0, (size_t)N_NODES * 4, stream);
    hipMemsetAsync(poolpart, 0, (size_t)NPART * NG * HC * 4, stream);

    k_deg<<<(EP + 255) / 256, 256, 0, stream>>>(ei, deg);
    k_scan1<<<SCAN_BLOCKS, 256, 0, stream>>>(deg, rowptr, part);
    k_scan2<<<1, 512, 0, stream>>>(part, rowptr, gstart);
    k_scan3<<<SCAN_BLOCKS, 256, 0, stream>>>(part, rowptr, cursor, x, xp, bat, gstart);
    k_scatter<<<(EP + 255) / 256, 256, 0, stream>>>(ei, cursor, csr);
    k_prepw2t<<<NBW2T + 1, 256, 0, stream>>>(W1, a1s, a1d, wprep, W2, W2T);
    k_layer1<<<N_NODES / 8, 256, 0, stream>>>(xp, rowptr, csr, W1, wprep, b1, x1b);
    // shift-by-one in-place GEMM (fp8 out): slice 0 -> T; slice i -> bytes of consumed x1 rows.
    for (int s = 0; s < nslices; s++) {
        fp8_t* outp = (s == 0) ? T : (h2hi + (size_t)(s - 1) * srows * HC);
        k_gemm2<<<dim3(4, (srows + 127) / 128), 256, 0, stream>>>(
            x1b, W2T, outp, s * srows, srows, a2s, a2d, al2s, al2d);
    }
    k_layer2pool<<<N_NODES / 8, 256, 0, stream>>>(T, h2hi, srows, al2s, al2d,
                                                  rowptr, csr, b2, bat, poolpart);
    k_poolcls<<<NG, 256, 0, stream>>>(poolpart, gstart, Wc, bc, out);
}

// Round 15
// 736.885 us; speedup vs baseline: 1.3861x; 1.3861x over previous
//
#include <hip/hip_runtime.h>
#include <math.h>

#define N_NODES 100000
#define N_EDGES 1600000
#define EP (N_EDGES + N_NODES)   // edges + self-loops = 1,700,000
#define NH 8
#define NC 64
#define NG 64
#define HC 512
#define SCAN_BLOCKS ((N_NODES + 255) / 256)   // 391
#define NPART 32                              // pooling atomic partitions
#define BPSTR 80                              // fp8 epilogue patch row stride (bytes, 16B-aligned)

typedef unsigned short bf16_t;
typedef unsigned char fp8_t;
typedef __attribute__((ext_vector_type(8))) short short8;
typedef __attribute__((ext_vector_type(4))) float floatx4;
typedef __attribute__((ext_vector_type(2))) float floatx2;

__device__ inline bf16_t f2bf(float f) {
    union { float f; unsigned int i; } x;
    x.f = f;
    unsigned int b = x.i;
    return (bf16_t)((b + 0x7fffu + ((b >> 16) & 1u)) >> 16);
}
__device__ inline fp8_t f2fp8(float f) {   // OCP e4m3fn, RNE, HW saturate
    int v = __builtin_amdgcn_cvt_pk_fp8_f32(f, f, 0, false);
    return (fp8_t)v;
}

// async global->LDS, 16B per lane; lds base must be wave-uniform (HW: base + lane*16)
__device__ inline void ldsload16(const void* g, void* l) {
    __builtin_amdgcn_global_load_lds(
        (const __attribute__((address_space(1))) unsigned int*)g,
        (__attribute__((address_space(3))) unsigned int*)l, 16, 0, 0);
}

// ---------------- prep (block NBW2T) + W2 transpose/bf16 (blocks 0..NBW2T-1) ----------------
#define NBW2T (HC * HC / 256)   // 1024
__global__ void k_prepw2t(const float* __restrict__ W1, const float* __restrict__ a1s,
                          const float* __restrict__ a1d, float* __restrict__ wprep,
                          const float* __restrict__ W2, bf16_t* __restrict__ W2T) {
    if (blockIdx.x == NBW2T) {
        int t = threadIdx.x;
        if (t < 48) {
            int isD = t >= 24;
            int tt = t % 24;
            int h = tt / 3, k = tt % 3;
            const float* a = isD ? a1d : a1s;
            float s = 0.f;
            for (int c = 0; c < 64; c++) s += W1[k * HC + h * 64 + c] * a[h * 64 + c];
            wprep[t] = s;
        }
        return;
    }
    int i = blockIdx.x * 256 + threadIdx.x;
    int n = i >> 9, kp = i & 511;
    int k = (kp & 7) * 64 + (kp >> 3);
    W2T[i] = f2bf(W2[k * HC + n]);
}

// ---------------- CSR build ----------------
__global__ void k_deg(const int* __restrict__ ei, int* __restrict__ deg) {
    int i = blockIdx.x * 256 + threadIdx.x;
    if (i >= EP) return;
    int d = (i < N_EDGES) ? ei[N_EDGES + i] : (i - N_EDGES);
    atomicAdd(&deg[d], 1);
}

__global__ void k_scan1(const int* __restrict__ deg, int* __restrict__ rowptr, int* __restrict__ part) {
    __shared__ int s[256];
    int t = threadIdx.x, i = blockIdx.x * 256 + t;
    int v = (i < N_NODES) ? deg[i] : 0;
    s[t] = v;
    __syncthreads();
    for (int off = 1; off < 256; off <<= 1) {
        int u = (t >= off) ? s[t - off] : 0;
        __syncthreads();
        s[t] += u;
        __syncthreads();
    }
    if (i < N_NODES) rowptr[i] = s[t] - v;
    if (t == 255) part[blockIdx.x] = s[t];
}

__global__ void k_scan2(int* __restrict__ part, int* __restrict__ rowptr, int* __restrict__ gstart) {
    __shared__ int s[512];
    int t = threadIdx.x;
    int v = (t < SCAN_BLOCKS) ? part[t] : 0;
    s[t] = v;
    __syncthreads();
    for (int off = 1; off < 512; off <<= 1) {
        int u = (t >= off) ? s[t - off] : 0;
        __syncthreads();
        s[t] += u;
        __syncthreads();
    }
    part[t] = s[t] - v;
    if (t == 0) rowptr[N_NODES] = EP;
    if (t <= NG) gstart[t] = N_NODES;   // fused init for graph bounds
}

// scan3 + cursor init + x padding + graph bounds, all fused
__global__ void k_scan3(const int* __restrict__ part, int* __restrict__ rowptr,
                        int* __restrict__ cursor, const float* __restrict__ x,
                        float* __restrict__ xp, const int* __restrict__ batch,
                        int* __restrict__ gstart) {
    int i = blockIdx.x * 256 + threadIdx.x;
    if (i < N_NODES) {
        int v = rowptr[i] + part[blockIdx.x];
        rowptr[i] = v;
        cursor[i] = v;
        xp[i * 4 + 0] = x[i * 3 + 0];
        xp[i * 4 + 1] = x[i * 3 + 1];
        xp[i * 4 + 2] = x[i * 3 + 2];
        xp[i * 4 + 3] = 0.f;
        int b = batch[i];
        if (i == 0) {
            for (int g = 0; g <= b; g++) gstart[g] = 0;
        } else {
            int bp = batch[i - 1];
            if (b != bp)
                for (int g = bp + 1; g <= b; g++) gstart[g] = i;
        }
    }
}

__global__ void k_scatter(const int* __restrict__ ei, int* __restrict__ cursor, int* __restrict__ csr) {
    int i = blockIdx.x * 256 + threadIdx.x;
    if (i >= EP) return;
    int s, d;
    if (i < N_EDGES) { s = ei[i]; d = ei[N_EDGES + i]; }
    else { s = i - N_EDGES; d = s; }
    int pos = atomicAdd(&cursor[d], 1);
    csr[pos] = s;
}

// ---------------- layer 1: 32 lanes per dst (2 dsts/wave) ----------------
__global__ __launch_bounds__(256) void k_layer1(
    const float* __restrict__ xp, const int* __restrict__ rowptr, const int* __restrict__ csr,
    const float* __restrict__ W1, const float* __restrict__ wprep, const float* __restrict__ b1,
    bf16_t* __restrict__ x1p) {
    __shared__ float w1s[1536];
    __shared__ float wp[48];
    int tid = threadIdx.x;
    for (int i = tid; i < 1536; i += 256) w1s[i] = W1[i];
    if (tid < 48) wp[tid] = wprep[tid];
    __syncthreads();
    int lane = tid & 63, wave = tid >> 6;
    int half = lane >> 5, l32 = lane & 31;
    int dst = blockIdx.x * 8 + wave * 2 + half;
    int rs = rowptr[dst], re = rowptr[dst + 1];
    float4 xd = *(const float4*)&xp[dst * 4];
    float ald[NH];
#pragma unroll
    for (int h = 0; h < NH; h++)
        ald[h] = xd.x * wp[24 + h * 3] + xd.y * wp[24 + h * 3 + 1] + xd.z * wp[24 + h * 3 + 2];
    float den[NH], c0[NH], c1[NH], c2[NH];
#pragma unroll
    for (int h = 0; h < NH; h++) { den[h] = 0.f; c0[h] = 0.f; c1[h] = 0.f; c2[h] = 0.f; }
    for (int base = rs; base < re; base += 32) {
        int e = base + l32;
        if (e < re) {
            int s = csr[e];
            float4 sv = *(const float4*)&xp[s * 4];
#pragma unroll
            for (int h = 0; h < NH; h++) {
                float ev = sv.x * wp[h * 3] + sv.y * wp[h * 3 + 1] + sv.z * wp[h * 3 + 2] + ald[h];
                ev = fmaxf(ev, 0.2f * ev);
                float w = __expf(ev);
                den[h] += w;
                c0[h] += w * sv.x;
                c1[h] += w * sv.y;
                c2[h] += w * sv.z;
            }
        }
    }
#pragma unroll
    for (int h = 0; h < NH; h++) {
#pragma unroll
        for (int off = 1; off < 32; off <<= 1) {
            den[h] += __shfl_xor(den[h], off, 64);
            c0[h] += __shfl_xor(c0[h], off, 64);
            c1[h] += __shfl_xor(c1[h], off, 64);
            c2[h] += __shfl_xor(c2[h], off, 64);
        }
    }
    bf16_t vbA[NH], vbB[NH];
#pragma unroll
    for (int h = 0; h < NH; h++) {
        int colA = h * 64 + l32;
        float vA = c0[h] * w1s[colA] + c1[h] * w1s[512 + colA] + c2[h] * w1s[1024 + colA];
        vA = vA / den[h] + b1[colA];
        vA = vA > 0.f ? vA : (__expf(vA) - 1.f);
        vbA[h] = f2bf(vA);
        int colB = colA + 32;
        float vB = c0[h] * w1s[colB] + c1[h] * w1s[512 + colB] + c2[h] * w1s[1024 + colB];
        vB = vB / den[h] + b1[colB];
        vB = vB > 0.f ? vB : (__expf(vB) - 1.f);
        vbB[h] = f2bf(vB);
    }
    uint4 oA, oB;
    oA.x = (unsigned int)vbA[0] | ((unsigned int)vbA[1] << 16);
    oA.y = (unsigned int)vbA[2] | ((unsigned int)vbA[3] << 16);
    oA.z = (unsigned int)vbA[4] | ((unsigned int)vbA[5] << 16);
    oA.w = (unsigned int)vbA[6] | ((unsigned int)vbA[7] << 16);
    oB.x = (unsigned int)vbB[0] | ((unsigned int)vbB[1] << 16);
    oB.y = (unsigned int)vbB[2] | ((unsigned int)vbB[3] << 16);
    oB.z = (unsigned int)vbB[4] | ((unsigned int)vbB[5] << 16);
    oB.w = (unsigned int)vbB[6] | ((unsigned int)vbB[7] << 16);
    *(uint4*)&x1p[(size_t)dst * HC + l32 * 8] = oA;
    *(uint4*)&x1p[(size_t)dst * HC + (l32 + 32) * 8] = oB;
}

// ---------------- GEMM2 128x128, BK=64, async staging; h2 OUTPUT IN FP8-e4m3 ----------------
__global__ __launch_bounds__(256) void k_gemm2(const bf16_t* __restrict__ A,
                                               const bf16_t* __restrict__ BT,
                                               fp8_t* __restrict__ Out,
                                               int row_base, int nrows,
                                               const float* __restrict__ a2s,
                                               const float* __restrict__ a2d,
                                               float* __restrict__ al2s,
                                               float* __restrict__ al2d) {
    __shared__ short smem[16384];          // As 8192 | Bs 8192 (128 rows x 64 shorts each)
    short* As = smem;
    short* Bs = smem + 8192;
    int tid = threadIdx.x;
    int lane = tid & 63, wave = tid >> 6;
    int wm = wave & 1, wn = wave >> 1;
    int lm = lane & 15, quad = lane >> 4;
    int gx = blockIdx.x, gy = blockIdx.y;
    int l8 = lane >> 3, lc8 = lane & 7;
    int sw = lc8 ^ l8;                     // swizzled global chunk for this lane
    const bf16_t* ga[4];
    const bf16_t* gb[4];
    short* la[4];
    short* lb[4];
#pragma unroll
    for (int it = 0; it < 4; it++) {
        int ar = gy * 128 + wave * 32 + it * 8 + l8;
        int arc = (ar < nrows) ? ar : 0;   // clamp OOB (rows never stored)
        ga[it] = A + (size_t)(row_base + arc) * HC + sw * 8;
        gb[it] = BT + (size_t)(gx * 128 + wave * 32 + it * 8 + l8) * HC + sw * 8;
        la[it] = As + (wave * 32 + it * 8) * 64;
        lb[it] = Bs + (wave * 32 + it * 8) * 64;
    }

    floatx4 acc[4][4];
#pragma unroll
    for (int mi = 0; mi < 4; mi++)
#pragma unroll
        for (int ni = 0; ni < 4; ni++) acc[mi][ni] = (floatx4){0.f, 0.f, 0.f, 0.f};

    int lmw = lm & 7;  // read-side swizzle key (row & 7)
    for (int k0 = 0; k0 < HC; k0 += 64) {
        __syncthreads();
#pragma unroll
        for (int it = 0; it < 4; it++) ldsload16(ga[it] + k0, la[it]);
#pragma unroll
        for (int it = 0; it < 4; it++) ldsload16(gb[it] + k0, lb[it]);
        __syncthreads();
        short8 af[4][2], bf[4][2];
#pragma unroll
        for (int mi = 0; mi < 4; mi++)
#pragma unroll
            for (int kk = 0; kk < 2; kk++) {
                int pos = (kk * 4 + quad) ^ lmw;
                af[mi][kk] = *(const short8*)&As[(wm * 64 + mi * 16 + lm) * 64 + pos * 8];
            }
#pragma unroll
        for (int ni = 0; ni < 4; ni++)
#pragma unroll
            for (int kk = 0; kk < 2; kk++) {
                int pos = (kk * 4 + quad) ^ lmw;
                bf[ni][kk] = *(const short8*)&Bs[(wn * 64 + ni * 16 + lm) * 64 + pos * 8];
            }
#pragma unroll
        for (int mi = 0; mi < 4; mi++)
#pragma unroll
            for (int ni = 0; ni < 4; ni++) {
                acc[mi][ni] = __builtin_amdgcn_mfma_f32_16x16x32_bf16(af[mi][0], bf[ni][0], acc[mi][ni], 0, 0, 0);
                acc[mi][ni] = __builtin_amdgcn_mfma_f32_16x16x32_bf16(af[mi][1], bf[ni][1], acc[mi][ni], 0, 0, 0);
            }
    }
    // ---- fused al2 from fp32 acc (EXACT logits; unaffected by fp8 h2 storage) ----
    int head = gx * 2 + wn;
    float a2sv[4], a2dv[4];
#pragma unroll
    for (int ni = 0; ni < 4; ni++) {
        int col = gx * 128 + wn * 64 + ni * 16 + lm;
        a2sv[ni] = a2s[col];
        a2dv[ni] = a2d[col];
    }
#pragma unroll
    for (int mi = 0; mi < 4; mi++) {
#pragma unroll
        for (int rg = 0; rg < 4; rg++) {
            int lrow = gy * 128 + wm * 64 + mi * 16 + quad * 4 + rg;
            float ps = 0.f, pd = 0.f;
#pragma unroll
            for (int ni = 0; ni < 4; ni++) {
                float v = acc[mi][ni][rg];
                ps += v * a2sv[ni];
                pd += v * a2dv[ni];
            }
#pragma unroll
            for (int off = 1; off < 16; off <<= 1) {
                ps += __shfl_xor(ps, off, 64);
                pd += __shfl_xor(pd, off, 64);
            }
            if (lrow < nrows && lm == 0) {
                int ar = row_base + lrow;
                al2s[ar * NH + head] = ps;
                al2d[ar * NH + head] = pd;
            }
        }
    }
    // ---- fp8 store via per-wave LDS byte patch (uint4 global stores, 64B/row segments) ----
    __syncthreads();
    unsigned char* bpatch = (unsigned char*)smem + wave * (32 * BPSTR);
#pragma unroll
    for (int p = 0; p < 2; p++) {
#pragma unroll
        for (int mih = 0; mih < 2; mih++) {
            int mi = p * 2 + mih;
#pragma unroll
            for (int ni = 0; ni < 4; ni++)
#pragma unroll
                for (int rg = 0; rg < 4; rg++) {
                    int rl = mih * 16 + quad * 4 + rg;
                    bpatch[rl * BPSTR + ni * 16 + lm] = f2fp8(acc[mi][ni][rg]);
                }
        }
        // same-wave LDS write->read in program order
#pragma unroll
        for (int it = 0; it < 2; it++) {
            int idx = it * 64 + lane;
            int rl = idx >> 2, c16 = idx & 3;
            uint4 v = *(uint4*)&bpatch[rl * BPSTR + c16 * 16];
            int lrow = gy * 128 + wm * 64 + p * 32 + rl;
            if (lrow < nrows)
                *(uint4*)&Out[(size_t)lrow * HC + wn * 64 + gx * 128 + c16 * 16] = v;
        }
        __syncthreads();
    }
}

// ---------------- layer 2 (r13-proven): 1 dst/wave, fp8 gathers unrolled x8, fused pool ----
__global__ __launch_bounds__(256) void k_layer2pool(
    const fp8_t* __restrict__ h2lo, const fp8_t* __restrict__ h2hi, int srows,
    const float* __restrict__ al2s, const float* __restrict__ al2d,
    const int* __restrict__ rowptr, const int* __restrict__ csr, const float* __restrict__ b2,
    const int* __restrict__ batch, float* __restrict__ poolpart) {
    __shared__ float wlds[4][512];
    __shared__ int slds[4][64];
    int tid = threadIdx.x, lane = tid & 63, wave = tid >> 6;
    int hme = lane >> 3;
    int dst = blockIdx.x * 4 + wave;
    int rs = rowptr[dst], re = rowptr[dst + 1];
    float4 d0 = *(const float4*)&al2d[dst * NH];
    float4 d1 = *(const float4*)&al2d[dst * NH + 4];
    float ald[NH] = {d0.x, d0.y, d0.z, d0.w, d1.x, d1.y, d1.z, d1.w};
    float den[NH], acc[8];
#pragma unroll
    for (int h = 0; h < NH; h++) den[h] = 0.f;
#pragma unroll
    for (int q = 0; q < 8; q++) acc[q] = 0.f;
    for (int base = rs; base < re; base += 64) {
        int e = base + lane;
        int cl = re - base; if (cl > 64) cl = 64;
        float w[NH];
        int s = 0;
        if (e < re) {
            s = csr[e];
            float4 p0 = *(const float4*)&al2s[s * NH];
            float4 p1 = *(const float4*)&al2s[s * NH + 4];
            float als[NH] = {p0.x, p0.y, p0.z, p0.w, p1.x, p1.y, p1.z, p1.w};
#pragma unroll
            for (int h = 0; h < NH; h++) {
                float ev = als[h] + ald[h];
                ev = fmaxf(ev, 0.2f * ev);
                w[h] = __expf(ev);
                den[h] += w[h];
            }
        } else {
#pragma unroll
            for (int h = 0; h < NH; h++) w[h] = 0.f;
        }
        slds[wave][lane] = s;
        *(float4*)&wlds[wave][lane * 8] = make_float4(w[0], w[1], w[2], w[3]);
        *(float4*)&wlds[wave][lane * 8 + 4] = make_float4(w[4], w[5], w[6], w[7]);
        // same-wave LDS write->read in program order; x8 unroll = 8 gathers in flight
        int j = 0;
        for (; j + 7 < cl; j += 8) {
            uint2 v[8];
            float wv[8];
#pragma unroll
            for (int u = 0; u < 8; u++) {
                int su = slds[wave][j + u];
                wv[u] = wlds[wave][(j + u) * 8 + hme];
                const fp8_t* bu = (su < srows) ? (h2lo + (size_t)su * HC)
                                               : (h2hi + (size_t)(su - srows) * HC);
                v[u] = *(const uint2*)&bu[lane * 8];
            }
#pragma unroll
            for (int u = 0; u < 8; u++) {
                floatx2 c;
                c = __builtin_amdgcn_cvt_pk_f32_fp8(v[u].x, false); acc[0] += wv[u] * c.x; acc[1] += wv[u] * c.y;
                c = __builtin_amdgcn_cvt_pk_f32_fp8(v[u].x, true);  acc[2] += wv[u] * c.x; acc[3] += wv[u] * c.y;
                c = __builtin_amdgcn_cvt_pk_f32_fp8(v[u].y, false); acc[4] += wv[u] * c.x; acc[5] += wv[u] * c.y;
                c = __builtin_amdgcn_cvt_pk_f32_fp8(v[u].y, true);  acc[6] += wv[u] * c.x; acc[7] += wv[u] * c.y;
            }
        }
        for (; j < cl; j++) {
            int sA = slds[wave][j];
            float wA = wlds[wave][j * 8 + hme];
            const fp8_t* bA = (sA < srows) ? (h2lo + (size_t)sA * HC)
                                           : (h2hi + (size_t)(sA - srows) * HC);
            uint2 vA = *(const uint2*)&bA[lane * 8];
            floatx2 c;
            c = __builtin_amdgcn_cvt_pk_f32_fp8(vA.x, false); acc[0] += wA * c.x; acc[1] += wA * c.y;
            c = __builtin_amdgcn_cvt_pk_f32_fp8(vA.x, true);  acc[2] += wA * c.x; acc[3] += wA * c.y;
            c = __builtin_amdgcn_cvt_pk_f32_fp8(vA.y, false); acc[4] += wA * c.x; acc[5] += wA * c.y;
            c = __builtin_amdgcn_cvt_pk_f32_fp8(vA.y, true);  acc[6] += wA * c.x; acc[7] += wA * c.y;
        }
    }
#pragma unroll
    for (int h = 0; h < NH; h++)
#pragma unroll
        for (int off = 1; off < 64; off <<= 1) den[h] += __shfl_xor(den[h], off, 64);
    float dd = den[0];
#pragma unroll
    for (int h = 1; h < NH; h++) dd = (hme == h) ? den[h] : dd;
    float dinv = 1.0f / dd;
    float4 ba = *(const float4*)&b2[lane * 8];
    float4 bb = *(const float4*)&b2[lane * 8 + 4];
    float bv[8] = {ba.x, ba.y, ba.z, ba.w, bb.x, bb.y, bb.z, bb.w};
    // stage post-ELU values in LDS, then atomics in COALESCED (h*64+lane) order
#pragma unroll
    for (int q = 0; q < 8; q++) {
        float v = acc[q] * dinv + bv[q];
        v = v > 0.f ? v : (__expf(v) - 1.f);
        wlds[wave][lane * 8 + q] = v;
    }
    int g = batch[dst];
    float* pp = poolpart + ((size_t)(blockIdx.x & (NPART - 1)) * NG + g) * HC;
#pragma unroll
    for (int h = 0; h < NH; h++)
        atomicAdd(&pp[h * 64 + lane], wlds[wave][h * 64 + lane]);
}

// ---------------- fused pool-reduce + classifier ----------------
__global__ __launch_bounds__(256) void k_poolcls(const float* __restrict__ poolpart,
                                                 const int* __restrict__ gstart,
                                                 const float* __restrict__ Wc,
                                                 const float* __restrict__ bc,
                                                 float* __restrict__ out) {
    __shared__ float pl[512];
    int g = blockIdx.x, t = threadIdx.x;
    for (int c = t; c < HC; c += 256) {
        float s = 0.f;
        for (int p = 0; p < NPART; p++) s += poolpart[(size_t)p * NG * HC + g * HC + c];
        pl[c] = s;
    }
    __syncthreads();
    if (t < 10) {
        float cnt = fmaxf((float)(gstart[g + 1] - gstart[g]), 1.0f);
        float acc = 0.f;
        for (int k = 0; k < HC; k++) acc += pl[k] * Wc[k * 10 + t];
        out[g * 10 + t] = acc / cnt + bc[t];
    }
}

extern "C" void kernel_launch(void* const* d_in, const int* in_sizes, int n_in,
                              void* d_out, int out_size, void* d_ws, size_t ws_size,
                              hipStream_t stream) {
    const float* x   = (const float*)d_in[0];
    const int*   ei  = (const int*)d_in[1];
    const int*   bat = (const int*)d_in[2];
    const float* W1  = (const float*)d_in[3];
    const float* a1s = (const float*)d_in[4];
    const float* a1d = (const float*)d_in[5];
    const float* b1  = (const float*)d_in[6];
    const float* W2  = (const float*)d_in[7];
    const float* a2s = (const float*)d_in[8];
    const float* a2d = (const float*)d_in[9];
    const float* b2  = (const float*)d_in[10];
    const float* Wc  = (const float*)d_in[11];
    const float* bc  = (const float*)d_in[12];
    float* out = (float*)d_out;

    char* ws = (char*)d_ws;
    size_t off = 0;
    auto alloc = [&](size_t bytes) {
        size_t o = off;
        off += (bytes + 255) & ~(size_t)255;
        return o;
    };
    float*  wprep    = (float*)(ws + alloc(48 * 4));
    int*    rowptr   = (int*)(ws + alloc((size_t)(N_NODES + 1) * 4));
    int*    deg      = (int*)(ws + alloc((size_t)N_NODES * 4));
    int*    cursor   = (int*)(ws + alloc((size_t)N_NODES * 4));
    int*    part     = (int*)(ws + alloc(512 * 4));
    int*    gstart   = (int*)(ws + alloc(65 * 4));
    float*  xp       = (float*)(ws + alloc((size_t)N_NODES * 4 * 4));
    int*    csr      = (int*)(ws + alloc((size_t)EP * 4));
    bf16_t* x1b      = (bf16_t*)(ws + alloc((size_t)N_NODES * HC * 2));
    float*  al2s     = (float*)(ws + alloc((size_t)N_NODES * NH * 4));
    float*  al2d     = (float*)(ws + alloc((size_t)N_NODES * NH * 4));
    float*  poolpart = (float*)(ws + alloc((size_t)NPART * NG * HC * 4));
    // W2T (512KB) aliases deg+cursor (800KB, dead after k_scatter)
    bf16_t* W2T = (bf16_t*)deg;

    // slice tier: h2 is FP8 (1 byte/elem) — largest slice temp that fits
    size_t rem = (ws_size > off) ? ws_size - off : 0;
    int nslices, srows;
    if (rem >= (size_t)N_NODES * HC)      { nslices = 1;  srows = N_NODES; }
    else if (rem >= (size_t)50000 * HC)   { nslices = 2;  srows = 50000; }
    else if (rem >= (size_t)25000 * HC)   { nslices = 4;  srows = 25000; }
    else if (rem >= (size_t)12500 * HC)   { nslices = 8;  srows = 12500; }
    else                                  { nslices = 16; srows = 6250; }
    fp8_t* T = (fp8_t*)(ws + alloc((size_t)srows * HC));
    fp8_t* h2hi = (fp8_t*)x1b;   // shift-by-one in-place region (byte-indexed)

    hipMemsetAsync(deg, 0, (size_t)N_NODES * 4, stream);
    hipMemsetAsync(poolpart, 0, (size_t)NPART * NG * HC * 4, stream);

    k_deg<<<(EP + 255) / 256, 256, 0, stream>>>(ei, deg);
    k_scan1<<<SCAN_BLOCKS, 256, 0, stream>>>(deg, rowptr, part);
    k_scan2<<<1, 512, 0, stream>>>(part, rowptr, gstart);
    k_scan3<<<SCAN_BLOCKS, 256, 0, stream>>>(part, rowptr, cursor, x, xp, bat, gstart);
    k_scatter<<<(EP + 255) / 256, 256, 0, stream>>>(ei, cursor, csr);
    k_prepw2t<<<NBW2T + 1, 256, 0, stream>>>(W1, a1s, a1d, wprep, W2, W2T);
    k_layer1<<<N_NODES / 8, 256, 0, stream>>>(xp, rowptr, csr, W1, wprep, b1, x1b);
    // shift-by-one in-place GEMM (fp8 out): slice 0 -> T; slice i -> bytes of consumed x1 rows.
    for (int s = 0; s < nslices; s++) {
        fp8_t* outp = (s == 0) ? T : (h2hi + (size_t)(s - 1) * srows * HC);
        k_gemm2<<<dim3(4, (srows + 127) / 128), 256, 0, stream>>>(
            x1b, W2T, outp, s * srows, srows, a2s, a2d, al2s, al2d);
    }
    k_layer2pool<<<N_NODES / 4, 256, 0, stream>>>(T, h2hi, srows, al2s, al2d,
                                                  rowptr, csr, b2, bat, poolpart);
    k_poolcls<<<NG, 256, 0, stream>>>(poolpart, gstart, Wc, bc, out);
}

// Round 16
// 718.048 us; speedup vs baseline: 1.4224x; 1.0262x over previous
//
#include <hip/hip_runtime.h>
#include <math.h>

#define N_NODES 100000
#define N_EDGES 1600000
#define EP (N_EDGES + N_NODES)   // edges + self-loops = 1,700,000
#define NH 8
#define NC 64
#define NG 64
#define HC 512
#define SCAN_BLOCKS ((N_NODES + 255) / 256)   // 391
#define NPART 32                              // pooling atomic partitions
#define BPSTR 80                              // fp8 epilogue patch row stride (bytes, 16B-aligned)

typedef unsigned short bf16_t;
typedef unsigned char fp8_t;
typedef __attribute__((ext_vector_type(8))) short short8;
typedef __attribute__((ext_vector_type(4))) float floatx4;
typedef __attribute__((ext_vector_type(2))) float floatx2;

__device__ inline bf16_t f2bf(float f) {
    union { float f; unsigned int i; } x;
    x.f = f;
    unsigned int b = x.i;
    return (bf16_t)((b + 0x7fffu + ((b >> 16) & 1u)) >> 16);
}
__device__ inline fp8_t f2fp8(float f) {   // OCP e4m3fn, RNE, HW saturate
    int v = __builtin_amdgcn_cvt_pk_fp8_f32(f, f, 0, false);
    return (fp8_t)v;
}

// async global->LDS, 16B per lane; lds base must be wave-uniform (HW: base + lane*16)
__device__ inline void ldsload16(const void* g, void* l) {
    __builtin_amdgcn_global_load_lds(
        (const __attribute__((address_space(1))) unsigned int*)g,
        (__attribute__((address_space(3))) unsigned int*)l, 16, 0, 0);
}

// ---------------- prep (block NBW2T) + W2 transpose/bf16 (blocks 0..NBW2T-1) ----------------
#define NBW2T (HC * HC / 256)   // 1024
__global__ void k_prepw2t(const float* __restrict__ W1, const float* __restrict__ a1s,
                          const float* __restrict__ a1d, float* __restrict__ wprep,
                          const float* __restrict__ W2, bf16_t* __restrict__ W2T) {
    if (blockIdx.x == NBW2T) {
        int t = threadIdx.x;
        if (t < 48) {
            int isD = t >= 24;
            int tt = t % 24;
            int h = tt / 3, k = tt % 3;
            const float* a = isD ? a1d : a1s;
            float s = 0.f;
            for (int c = 0; c < 64; c++) s += W1[k * HC + h * 64 + c] * a[h * 64 + c];
            wprep[t] = s;
        }
        return;
    }
    int i = blockIdx.x * 256 + threadIdx.x;
    int n = i >> 9, kp = i & 511;
    int k = (kp & 7) * 64 + (kp >> 3);
    W2T[i] = f2bf(W2[k * HC + n]);
}

// ---------------- CSR build ----------------
__global__ void k_deg(const int* __restrict__ ei, int* __restrict__ deg) {
    int i = blockIdx.x * 256 + threadIdx.x;
    if (i >= EP) return;
    int d = (i < N_EDGES) ? ei[N_EDGES + i] : (i - N_EDGES);
    atomicAdd(&deg[d], 1);
}

__global__ void k_scan1(const int* __restrict__ deg, int* __restrict__ rowptr, int* __restrict__ part) {
    __shared__ int s[256];
    int t = threadIdx.x, i = blockIdx.x * 256 + t;
    int v = (i < N_NODES) ? deg[i] : 0;
    s[t] = v;
    __syncthreads();
    for (int off = 1; off < 256; off <<= 1) {
        int u = (t >= off) ? s[t - off] : 0;
        __syncthreads();
        s[t] += u;
        __syncthreads();
    }
    if (i < N_NODES) rowptr[i] = s[t] - v;
    if (t == 255) part[blockIdx.x] = s[t];
}

__global__ void k_scan2(int* __restrict__ part, int* __restrict__ rowptr, int* __restrict__ gstart) {
    __shared__ int s[512];
    int t = threadIdx.x;
    int v = (t < SCAN_BLOCKS) ? part[t] : 0;
    s[t] = v;
    __syncthreads();
    for (int off = 1; off < 512; off <<= 1) {
        int u = (t >= off) ? s[t - off] : 0;
        __syncthreads();
        s[t] += u;
        __syncthreads();
    }
    part[t] = s[t] - v;
    if (t == 0) rowptr[N_NODES] = EP;
    if (t <= NG) gstart[t] = N_NODES;   // fused init for graph bounds
}

// scan3 + cursor init + x padding + graph bounds, all fused
__global__ void k_scan3(const int* __restrict__ part, int* __restrict__ rowptr,
                        int* __restrict__ cursor, const float* __restrict__ x,
                        float* __restrict__ xp, const int* __restrict__ batch,
                        int* __restrict__ gstart) {
    int i = blockIdx.x * 256 + threadIdx.x;
    if (i < N_NODES) {
        int v = rowptr[i] + part[blockIdx.x];
        rowptr[i] = v;
        cursor[i] = v;
        xp[i * 4 + 0] = x[i * 3 + 0];
        xp[i * 4 + 1] = x[i * 3 + 1];
        xp[i * 4 + 2] = x[i * 3 + 2];
        xp[i * 4 + 3] = 0.f;
        int b = batch[i];
        if (i == 0) {
            for (int g = 0; g <= b; g++) gstart[g] = 0;
        } else {
            int bp = batch[i - 1];
            if (b != bp)
                for (int g = bp + 1; g <= b; g++) gstart[g] = i;
        }
    }
}

__global__ void k_scatter(const int* __restrict__ ei, int* __restrict__ cursor, int* __restrict__ csr) {
    int i = blockIdx.x * 256 + threadIdx.x;
    if (i >= EP) return;
    int s, d;
    if (i < N_EDGES) { s = ei[i]; d = ei[N_EDGES + i]; }
    else { s = i - N_EDGES; d = s; }
    int pos = atomicAdd(&cursor[d], 1);
    csr[pos] = s;
}

// ---------------- layer 1: 32 lanes per dst (2 dsts/wave) ----------------
__global__ __launch_bounds__(256) void k_layer1(
    const float* __restrict__ xp, const int* __restrict__ rowptr, const int* __restrict__ csr,
    const float* __restrict__ W1, const float* __restrict__ wprep, const float* __restrict__ b1,
    bf16_t* __restrict__ x1p) {
    __shared__ float w1s[1536];
    __shared__ float wp[48];
    int tid = threadIdx.x;
    for (int i = tid; i < 1536; i += 256) w1s[i] = W1[i];
    if (tid < 48) wp[tid] = wprep[tid];
    __syncthreads();
    int lane = tid & 63, wave = tid >> 6;
    int half = lane >> 5, l32 = lane & 31;
    int dst = blockIdx.x * 8 + wave * 2 + half;
    int rs = rowptr[dst], re = rowptr[dst + 1];
    float4 xd = *(const float4*)&xp[dst * 4];
    float ald[NH];
#pragma unroll
    for (int h = 0; h < NH; h++)
        ald[h] = xd.x * wp[24 + h * 3] + xd.y * wp[24 + h * 3 + 1] + xd.z * wp[24 + h * 3 + 2];
    float den[NH], c0[NH], c1[NH], c2[NH];
#pragma unroll
    for (int h = 0; h < NH; h++) { den[h] = 0.f; c0[h] = 0.f; c1[h] = 0.f; c2[h] = 0.f; }
    for (int base = rs; base < re; base += 32) {
        int e = base + l32;
        if (e < re) {
            int s = csr[e];
            float4 sv = *(const float4*)&xp[s * 4];
#pragma unroll
            for (int h = 0; h < NH; h++) {
                float ev = sv.x * wp[h * 3] + sv.y * wp[h * 3 + 1] + sv.z * wp[h * 3 + 2] + ald[h];
                ev = fmaxf(ev, 0.2f * ev);
                float w = __expf(ev);
                den[h] += w;
                c0[h] += w * sv.x;
                c1[h] += w * sv.y;
                c2[h] += w * sv.z;
            }
        }
    }
#pragma unroll
    for (int h = 0; h < NH; h++) {
#pragma unroll
        for (int off = 1; off < 32; off <<= 1) {
            den[h] += __shfl_xor(den[h], off, 64);
            c0[h] += __shfl_xor(c0[h], off, 64);
            c1[h] += __shfl_xor(c1[h], off, 64);
            c2[h] += __shfl_xor(c2[h], off, 64);
        }
    }
    bf16_t vbA[NH], vbB[NH];
#pragma unroll
    for (int h = 0; h < NH; h++) {
        int colA = h * 64 + l32;
        float vA = c0[h] * w1s[colA] + c1[h] * w1s[512 + colA] + c2[h] * w1s[1024 + colA];
        vA = vA / den[h] + b1[colA];
        vA = vA > 0.f ? vA : (__expf(vA) - 1.f);
        vbA[h] = f2bf(vA);
        int colB = colA + 32;
        float vB = c0[h] * w1s[colB] + c1[h] * w1s[512 + colB] + c2[h] * w1s[1024 + colB];
        vB = vB / den[h] + b1[colB];
        vB = vB > 0.f ? vB : (__expf(vB) - 1.f);
        vbB[h] = f2bf(vB);
    }
    uint4 oA, oB;
    oA.x = (unsigned int)vbA[0] | ((unsigned int)vbA[1] << 16);
    oA.y = (unsigned int)vbA[2] | ((unsigned int)vbA[3] << 16);
    oA.z = (unsigned int)vbA[4] | ((unsigned int)vbA[5] << 16);
    oA.w = (unsigned int)vbA[6] | ((unsigned int)vbA[7] << 16);
    oB.x = (unsigned int)vbB[0] | ((unsigned int)vbB[1] << 16);
    oB.y = (unsigned int)vbB[2] | ((unsigned int)vbB[3] << 16);
    oB.z = (unsigned int)vbB[4] | ((unsigned int)vbB[5] << 16);
    oB.w = (unsigned int)vbB[6] | ((unsigned int)vbB[7] << 16);
    *(uint4*)&x1p[(size_t)dst * HC + l32 * 8] = oA;
    *(uint4*)&x1p[(size_t)dst * HC + (l32 + 32) * 8] = oB;
}

// ---------------- GEMM2 128x128, BK=64, async staging; h2 OUTPUT IN FP8-e4m3 ----------------
__global__ __launch_bounds__(256) void k_gemm2(const bf16_t* __restrict__ A,
                                               const bf16_t* __restrict__ BT,
                                               fp8_t* __restrict__ Out,
                                               int row_base, int nrows,
                                               const float* __restrict__ a2s,
                                               const float* __restrict__ a2d,
                                               float* __restrict__ al2s,
                                               float* __restrict__ al2d) {
    __shared__ short smem[16384];          // As 8192 | Bs 8192 (128 rows x 64 shorts each)
    short* As = smem;
    short* Bs = smem + 8192;
    int tid = threadIdx.x;
    int lane = tid & 63, wave = tid >> 6;
    int wm = wave & 1, wn = wave >> 1;
    int lm = lane & 15, quad = lane >> 4;
    int gx = blockIdx.x, gy = blockIdx.y;
    int l8 = lane >> 3, lc8 = lane & 7;
    int sw = lc8 ^ l8;                     // swizzled global chunk for this lane
    const bf16_t* ga[4];
    const bf16_t* gb[4];
    short* la[4];
    short* lb[4];
#pragma unroll
    for (int it = 0; it < 4; it++) {
        int ar = gy * 128 + wave * 32 + it * 8 + l8;
        int arc = (ar < nrows) ? ar : 0;   // clamp OOB (rows never stored)
        ga[it] = A + (size_t)(row_base + arc) * HC + sw * 8;
        gb[it] = BT + (size_t)(gx * 128 + wave * 32 + it * 8 + l8) * HC + sw * 8;
        la[it] = As + (wave * 32 + it * 8) * 64;
        lb[it] = Bs + (wave * 32 + it * 8) * 64;
    }

    floatx4 acc[4][4];
#pragma unroll
    for (int mi = 0; mi < 4; mi++)
#pragma unroll
        for (int ni = 0; ni < 4; ni++) acc[mi][ni] = (floatx4){0.f, 0.f, 0.f, 0.f};

    int lmw = lm & 7;  // read-side swizzle key (row & 7)
    for (int k0 = 0; k0 < HC; k0 += 64) {
        __syncthreads();
#pragma unroll
        for (int it = 0; it < 4; it++) ldsload16(ga[it] + k0, la[it]);
#pragma unroll
        for (int it = 0; it < 4; it++) ldsload16(gb[it] + k0, lb[it]);
        __syncthreads();
        short8 af[4][2], bf[4][2];
#pragma unroll
        for (int mi = 0; mi < 4; mi++)
#pragma unroll
            for (int kk = 0; kk < 2; kk++) {
                int pos = (kk * 4 + quad) ^ lmw;
                af[mi][kk] = *(const short8*)&As[(wm * 64 + mi * 16 + lm) * 64 + pos * 8];
            }
#pragma unroll
        for (int ni = 0; ni < 4; ni++)
#pragma unroll
            for (int kk = 0; kk < 2; kk++) {
                int pos = (kk * 4 + quad) ^ lmw;
                bf[ni][kk] = *(const short8*)&Bs[(wn * 64 + ni * 16 + lm) * 64 + pos * 8];
            }
#pragma unroll
        for (int mi = 0; mi < 4; mi++)
#pragma unroll
            for (int ni = 0; ni < 4; ni++) {
                acc[mi][ni] = __builtin_amdgcn_mfma_f32_16x16x32_bf16(af[mi][0], bf[ni][0], acc[mi][ni], 0, 0, 0);
                acc[mi][ni] = __builtin_amdgcn_mfma_f32_16x16x32_bf16(af[mi][1], bf[ni][1], acc[mi][ni], 0, 0, 0);
            }
    }
    // ---- fused al2 from fp32 acc (EXACT logits; unaffected by fp8 h2 storage) ----
    int head = gx * 2 + wn;
    float a2sv[4], a2dv[4];
#pragma unroll
    for (int ni = 0; ni < 4; ni++) {
        int col = gx * 128 + wn * 64 + ni * 16 + lm;
        a2sv[ni] = a2s[col];
        a2dv[ni] = a2d[col];
    }
#pragma unroll
    for (int mi = 0; mi < 4; mi++) {
#pragma unroll
        for (int rg = 0; rg < 4; rg++) {
            int lrow = gy * 128 + wm * 64 + mi * 16 + quad * 4 + rg;
            float ps = 0.f, pd = 0.f;
#pragma unroll
            for (int ni = 0; ni < 4; ni++) {
                float v = acc[mi][ni][rg];
                ps += v * a2sv[ni];
                pd += v * a2dv[ni];
            }
#pragma unroll
            for (int off = 1; off < 16; off <<= 1) {
                ps += __shfl_xor(ps, off, 64);
                pd += __shfl_xor(pd, off, 64);
            }
            if (lrow < nrows && lm == 0) {
                int ar = row_base + lrow;
                al2s[ar * NH + head] = ps;
                al2d[ar * NH + head] = pd;
            }
        }
    }
    // ---- fp8 store via per-wave LDS byte patch (uint4 global stores, 64B/row segments) ----
    __syncthreads();
    unsigned char* bpatch = (unsigned char*)smem + wave * (32 * BPSTR);
#pragma unroll
    for (int p = 0; p < 2; p++) {
#pragma unroll
        for (int mih = 0; mih < 2; mih++) {
            int mi = p * 2 + mih;
#pragma unroll
            for (int ni = 0; ni < 4; ni++)
#pragma unroll
                for (int rg = 0; rg < 4; rg++) {
                    int rl = mih * 16 + quad * 4 + rg;
                    bpatch[rl * BPSTR + ni * 16 + lm] = f2fp8(acc[mi][ni][rg]);
                }
        }
        // same-wave LDS write->read in program order
#pragma unroll
        for (int it = 0; it < 2; it++) {
            int idx = it * 64 + lane;
            int rl = idx >> 2, c16 = idx & 3;
            uint4 v = *(uint4*)&bpatch[rl * BPSTR + c16 * 16];
            int lrow = gy * 128 + wm * 64 + p * 32 + rl;
            if (lrow < nrows)
                *(uint4*)&Out[(size_t)lrow * HC + wn * 64 + gx * 128 + c16 * 16] = v;
        }
        __syncthreads();
    }
}

// ---------------- layer 2: ONE dst per 64-thread block (no intra-block skew), x4 unroll ----
__global__ __launch_bounds__(64) void k_layer2pool(
    const fp8_t* __restrict__ h2lo, const fp8_t* __restrict__ h2hi, int srows,
    const float* __restrict__ al2s, const float* __restrict__ al2d,
    const int* __restrict__ rowptr, const int* __restrict__ csr, const float* __restrict__ b2,
    const int* __restrict__ batch, float* __restrict__ poolpart) {
    __shared__ float wlds[512];
    __shared__ int slds[64];
    int lane = threadIdx.x;
    int hme = lane >> 3;
    int dst = blockIdx.x;
    int rs = rowptr[dst], re = rowptr[dst + 1];
    float4 d0 = *(const float4*)&al2d[dst * NH];
    float4 d1 = *(const float4*)&al2d[dst * NH + 4];
    float ald[NH] = {d0.x, d0.y, d0.z, d0.w, d1.x, d1.y, d1.z, d1.w};
    float den[NH], acc[8];
#pragma unroll
    for (int h = 0; h < NH; h++) den[h] = 0.f;
#pragma unroll
    for (int q = 0; q < 8; q++) acc[q] = 0.f;
    for (int base = rs; base < re; base += 64) {
        int e = base + lane;
        int cl = re - base; if (cl > 64) cl = 64;
        float w[NH];
        int s = 0;
        if (e < re) {
            s = csr[e];
            float4 p0 = *(const float4*)&al2s[s * NH];
            float4 p1 = *(const float4*)&al2s[s * NH + 4];
            float als[NH] = {p0.x, p0.y, p0.z, p0.w, p1.x, p1.y, p1.z, p1.w};
#pragma unroll
            for (int h = 0; h < NH; h++) {
                float ev = als[h] + ald[h];
                ev = fmaxf(ev, 0.2f * ev);
                w[h] = __expf(ev);
                den[h] += w[h];
            }
        } else {
#pragma unroll
            for (int h = 0; h < NH; h++) w[h] = 0.f;
        }
        slds[lane] = s;
        *(float4*)&wlds[lane * 8] = make_float4(w[0], w[1], w[2], w[3]);
        *(float4*)&wlds[lane * 8 + 4] = make_float4(w[4], w[5], w[6], w[7]);
        // same-wave LDS write->read in program order; x4 unroll = 4 gathers in flight
        int j = 0;
        for (; j + 3 < cl; j += 4) {
            int s0 = slds[j + 0], s1 = slds[j + 1];
            int s2 = slds[j + 2], s3 = slds[j + 3];
            float w0 = wlds[(j + 0) * 8 + hme];
            float w1 = wlds[(j + 1) * 8 + hme];
            float w2 = wlds[(j + 2) * 8 + hme];
            float w3 = wlds[(j + 3) * 8 + hme];
            const fp8_t* b0 = (s0 < srows) ? (h2lo + (size_t)s0 * HC) : (h2hi + (size_t)(s0 - srows) * HC);
            const fp8_t* b1p = (s1 < srows) ? (h2lo + (size_t)s1 * HC) : (h2hi + (size_t)(s1 - srows) * HC);
            const fp8_t* b2p = (s2 < srows) ? (h2lo + (size_t)s2 * HC) : (h2hi + (size_t)(s2 - srows) * HC);
            const fp8_t* b3p = (s3 < srows) ? (h2lo + (size_t)s3 * HC) : (h2hi + (size_t)(s3 - srows) * HC);
            uint2 v0 = *(const uint2*)&b0[lane * 8];
            uint2 v1 = *(const uint2*)&b1p[lane * 8];
            uint2 v2 = *(const uint2*)&b2p[lane * 8];
            uint2 v3 = *(const uint2*)&b3p[lane * 8];
            floatx2 c;
            c = __builtin_amdgcn_cvt_pk_f32_fp8(v0.x, false); acc[0] += w0 * c.x; acc[1] += w0 * c.y;
            c = __builtin_amdgcn_cvt_pk_f32_fp8(v0.x, true);  acc[2] += w0 * c.x; acc[3] += w0 * c.y;
            c = __builtin_amdgcn_cvt_pk_f32_fp8(v0.y, false); acc[4] += w0 * c.x; acc[5] += w0 * c.y;
            c = __builtin_amdgcn_cvt_pk_f32_fp8(v0.y, true);  acc[6] += w0 * c.x; acc[7] += w0 * c.y;
            c = __builtin_amdgcn_cvt_pk_f32_fp8(v1.x, false); acc[0] += w1 * c.x; acc[1] += w1 * c.y;
            c = __builtin_amdgcn_cvt_pk_f32_fp8(v1.x, true);  acc[2] += w1 * c.x; acc[3] += w1 * c.y;
            c = __builtin_amdgcn_cvt_pk_f32_fp8(v1.y, false); acc[4] += w1 * c.x; acc[5] += w1 * c.y;
            c = __builtin_amdgcn_cvt_pk_f32_fp8(v1.y, true);  acc[6] += w1 * c.x; acc[7] += w1 * c.y;
            c = __builtin_amdgcn_cvt_pk_f32_fp8(v2.x, false); acc[0] += w2 * c.x; acc[1] += w2 * c.y;
            c = __builtin_amdgcn_cvt_pk_f32_fp8(v2.x, true);  acc[2] += w2 * c.x; acc[3] += w2 * c.y;
            c = __builtin_amdgcn_cvt_pk_f32_fp8(v2.y, false); acc[4] += w2 * c.x; acc[5] += w2 * c.y;
            c = __builtin_amdgcn_cvt_pk_f32_fp8(v2.y, true);  acc[6] += w2 * c.x; acc[7] += w2 * c.y;
            c = __builtin_amdgcn_cvt_pk_f32_fp8(v3.x, false); acc[0] += w3 * c.x; acc[1] += w3 * c.y;
            c = __builtin_amdgcn_cvt_pk_f32_fp8(v3.x, true);  acc[2] += w3 * c.x; acc[3] += w3 * c.y;
            c = __builtin_amdgcn_cvt_pk_f32_fp8(v3.y, false); acc[4] += w3 * c.x; acc[5] += w3 * c.y;
            c = __builtin_amdgcn_cvt_pk_f32_fp8(v3.y, true);  acc[6] += w3 * c.x; acc[7] += w3 * c.y;
        }
        for (; j < cl; j++) {
            int sA = slds[j];
            float wA = wlds[j * 8 + hme];
            const fp8_t* bA = (sA < srows) ? (h2lo + (size_t)sA * HC) : (h2hi + (size_t)(sA - srows) * HC);
            uint2 vA = *(const uint2*)&bA[lane * 8];
            floatx2 c;
            c = __builtin_amdgcn_cvt_pk_f32_fp8(vA.x, false); acc[0] += wA * c.x; acc[1] += wA * c.y;
            c = __builtin_amdgcn_cvt_pk_f32_fp8(vA.x, true);  acc[2] += wA * c.x; acc[3] += wA * c.y;
            c = __builtin_amdgcn_cvt_pk_f32_fp8(vA.y, false); acc[4] += wA * c.x; acc[5] += wA * c.y;
            c = __builtin_amdgcn_cvt_pk_f32_fp8(vA.y, true);  acc[6] += wA * c.x; acc[7] += wA * c.y;
        }
    }
#pragma unroll
    for (int h = 0; h < NH; h++)
#pragma unroll
        for (int off = 1; off < 64; off <<= 1) den[h] += __shfl_xor(den[h], off, 64);
    float dd = den[0];
#pragma unroll
    for (int h = 1; h < NH; h++) dd = (hme == h) ? den[h] : dd;
    float dinv = 1.0f / dd;
    float4 ba = *(const float4*)&b2[lane * 8];
    float4 bb = *(const float4*)&b2[lane * 8 + 4];
    float bv[8] = {ba.x, ba.y, ba.z, ba.w, bb.x, bb.y, bb.z, bb.w};
    // stage post-ELU values in LDS, then atomics in COALESCED (h*64+lane) order
#pragma unroll
    for (int q = 0; q < 8; q++) {
        float v = acc[q] * dinv + bv[q];
        v = v > 0.f ? v : (__expf(v) - 1.f);
        wlds[lane * 8 + q] = v;
    }
    int g = batch[dst];
    float* pp = poolpart + ((size_t)(blockIdx.x & (NPART - 1)) * NG + g) * HC;
#pragma unroll
    for (int h = 0; h < NH; h++)
        atomicAdd(&pp[h * 64 + lane], wlds[h * 64 + lane]);
}

// ---------------- fused pool-reduce + classifier ----------------
__global__ __launch_bounds__(256) void k_poolcls(const float* __restrict__ poolpart,
                                                 const int* __restrict__ gstart,
                                                 const float* __restrict__ Wc,
                                                 const float* __restrict__ bc,
                                                 float* __restrict__ out) {
    __shared__ float pl[512];
    int g = blockIdx.x, t = threadIdx.x;
    for (int c = t; c < HC; c += 256) {
        float s = 0.f;
        for (int p = 0; p < NPART; p++) s += poolpart[(size_t)p * NG * HC + g * HC + c];
        pl[c] = s;
    }
    __syncthreads();
    if (t < 10) {
        float cnt = fmaxf((float)(gstart[g + 1] - gstart[g]), 1.0f);
        float acc = 0.f;
        for (int k = 0; k < HC; k++) acc += pl[k] * Wc[k * 10 + t];
        out[g * 10 + t] = acc / cnt + bc[t];
    }
}

extern "C" void kernel_launch(void* const* d_in, const int* in_sizes, int n_in,
                              void* d_out, int out_size, void* d_ws, size_t ws_size,
                              hipStream_t stream) {
    const float* x   = (const float*)d_in[0];
    const int*   ei  = (const int*)d_in[1];
    const int*   bat = (const int*)d_in[2];
    const float* W1  = (const float*)d_in[3];
    const float* a1s = (const float*)d_in[4];
    const float* a1d = (const float*)d_in[5];
    const float* b1  = (const float*)d_in[6];
    const float* W2  = (const float*)d_in[7];
    const float* a2s = (const float*)d_in[8];
    const float* a2d = (const float*)d_in[9];
    const float* b2  = (const float*)d_in[10];
    const float* Wc  = (const float*)d_in[11];
    const float* bc  = (const float*)d_in[12];
    float* out = (float*)d_out;

    char* ws = (char*)d_ws;
    size_t off = 0;
    auto alloc = [&](size_t bytes) {
        size_t o = off;
        off += (bytes + 255) & ~(size_t)255;
        return o;
    };
    float*  wprep    = (float*)(ws + alloc(48 * 4));
    int*    rowptr   = (int*)(ws + alloc((size_t)(N_NODES + 1) * 4));
    int*    deg      = (int*)(ws + alloc((size_t)N_NODES * 4));
    int*    cursor   = (int*)(ws + alloc((size_t)N_NODES * 4));
    int*    part     = (int*)(ws + alloc(512 * 4));
    int*    gstart   = (int*)(ws + alloc(65 * 4));
    float*  xp       = (float*)(ws + alloc((size_t)N_NODES * 4 * 4));
    int*    csr      = (int*)(ws + alloc((size_t)EP * 4));
    bf16_t* x1b      = (bf16_t*)(ws + alloc((size_t)N_NODES * HC * 2));
    float*  al2s     = (float*)(ws + alloc((size_t)N_NODES * NH * 4));
    float*  al2d     = (float*)(ws + alloc((size_t)N_NODES * NH * 4));
    float*  poolpart = (float*)(ws + alloc((size_t)NPART * NG * HC * 4));
    // W2T (512KB) aliases deg+cursor (800KB, dead after k_scatter)
    bf16_t* W2T = (bf16_t*)deg;

    // slice tier: h2 is FP8 (1 byte/elem) — largest slice temp that fits
    size_t rem = (ws_size > off) ? ws_size - off : 0;
    int nslices, srows;
    if (rem >= (size_t)N_NODES * HC)      { nslices = 1;  srows = N_NODES; }
    else if (rem >= (size_t)50000 * HC)   { nslices = 2;  srows = 50000; }
    else if (rem >= (size_t)25000 * HC)   { nslices = 4;  srows = 25000; }
    else if (rem >= (size_t)12500 * HC)   { nslices = 8;  srows = 12500; }
    else                                  { nslices = 16; srows = 6250; }
    fp8_t* T = (fp8_t*)(ws + alloc((size_t)srows * HC));
    fp8_t* h2hi = (fp8_t*)x1b;   // shift-by-one in-place region (byte-indexed)

    hipMemsetAsync(deg, 0, (size_t)N_NODES * 4, stream);
    hipMemsetAsync(poolpart, 0, (size_t)NPART * NG * HC * 4, stream);

    k_deg<<<(EP + 255) / 256, 256, 0, stream>>>(ei, deg);
    k_scan1<<<SCAN_BLOCKS, 256, 0, stream>>>(deg, rowptr, part);
    k_scan2<<<1, 512, 0, stream>>>(part, rowptr, gstart);
    k_scan3<<<SCAN_BLOCKS, 256, 0, stream>>>(part, rowptr, cursor, x, xp, bat, gstart);
    k_scatter<<<(EP + 255) / 256, 256, 0, stream>>>(ei, cursor, csr);
    k_prepw2t<<<NBW2T + 1, 256, 0, stream>>>(W1, a1s, a1d, wprep, W2, W2T);
    k_layer1<<<N_NODES / 8, 256, 0, stream>>>(xp, rowptr, csr, W1, wprep, b1, x1b);
    // shift-by-one in-place GEMM (fp8 out): slice 0 -> T; slice i -> bytes of consumed x1 rows.
    for (int s = 0; s < nslices; s++) {
        fp8_t* outp = (s == 0) ? T : (h2hi + (size_t)(s - 1) * srows * HC);
        k_gemm2<<<dim3(4, (srows + 127) / 128), 256, 0, stream>>>(
            x1b, W2T, outp, s * srows, srows, a2s, a2d, al2s, al2d);
    }
    k_layer2pool<<<N_NODES, 64, 0, stream>>>(T, h2hi, srows, al2s, al2d,
                                             rowptr, csr, b2, bat, poolpart);
    k_poolcls<<<NG, 256, 0, stream>>>(poolpart, gstart, Wc, bc, out);
}

// Round 17
// 715.572 us; speedup vs baseline: 1.4274x; 1.0035x over previous
//
#include <hip/hip_runtime.h>
#include <math.h>

#define N_NODES 100000
#define N_EDGES 1600000
#define EP (N_EDGES + N_NODES)   // edges + self-loops = 1,700,000
#define NH 8
#define NC 64
#define NG 64
#define HC 512
#define SCAN_BLOCKS ((N_NODES + 255) / 256)   // 391
#define NPART 32                              // pooling atomic partitions
#define BPSTR 80                              // fp8 epilogue patch row stride (bytes, 16B-aligned)

typedef unsigned short bf16_t;
typedef unsigned char fp8_t;
typedef __attribute__((ext_vector_type(8))) short short8;
typedef __attribute__((ext_vector_type(4))) float floatx4;
typedef __attribute__((ext_vector_type(2))) float floatx2;

__device__ inline float bf2f(bf16_t u) {
    union { unsigned int i; float f; } x;
    x.i = (unsigned int)u << 16;
    return x.f;
}
__device__ inline bf16_t f2bf(float f) {
    union { float f; unsigned int i; } x;
    x.f = f;
    unsigned int b = x.i;
    return (bf16_t)((b + 0x7fffu + ((b >> 16) & 1u)) >> 16);
}
__device__ inline fp8_t f2fp8(float f) {   // OCP e4m3fn, RNE, HW saturate
    int v = __builtin_amdgcn_cvt_pk_fp8_f32(f, f, 0, false);
    return (fp8_t)v;
}

// async global->LDS, 16B per lane; lds base must be wave-uniform (HW: base + lane*16)
__device__ inline void ldsload16(const void* g, void* l) {
    __builtin_amdgcn_global_load_lds(
        (const __attribute__((address_space(1))) unsigned int*)g,
        (__attribute__((address_space(3))) unsigned int*)l, 16, 0, 0);
}

// ---------------- prep (block NBW2T) + W2 transpose/bf16 (blocks 0..NBW2T-1) ----------------
#define NBW2T (HC * HC / 256)   // 1024
__global__ void k_prepw2t(const float* __restrict__ W1, const float* __restrict__ a1s,
                          const float* __restrict__ a1d, float* __restrict__ wprep,
                          const float* __restrict__ W2, bf16_t* __restrict__ W2T) {
    if (blockIdx.x == NBW2T) {
        int t = threadIdx.x;
        if (t < 48) {
            int isD = t >= 24;
            int tt = t % 24;
            int h = tt / 3, k = tt % 3;
            const float* a = isD ? a1d : a1s;
            float s = 0.f;
            for (int c = 0; c < 64; c++) s += W1[k * HC + h * 64 + c] * a[h * 64 + c];
            wprep[t] = s;
        }
        return;
    }
    int i = blockIdx.x * 256 + threadIdx.x;
    int n = i >> 9, kp = i & 511;
    int k = (kp & 7) * 64 + (kp >> 3);
    W2T[i] = f2bf(W2[k * HC + n]);
}

// ---------------- CSR build ----------------
__global__ void k_deg(const int* __restrict__ ei, int* __restrict__ deg) {
    int i = blockIdx.x * 256 + threadIdx.x;
    if (i >= EP) return;
    int d = (i < N_EDGES) ? ei[N_EDGES + i] : (i - N_EDGES);
    atomicAdd(&deg[d], 1);
}

__global__ void k_scan1(const int* __restrict__ deg, int* __restrict__ rowptr, int* __restrict__ part) {
    __shared__ int s[256];
    int t = threadIdx.x, i = blockIdx.x * 256 + t;
    int v = (i < N_NODES) ? deg[i] : 0;
    s[t] = v;
    __syncthreads();
    for (int off = 1; off < 256; off <<= 1) {
        int u = (t >= off) ? s[t - off] : 0;
        __syncthreads();
        s[t] += u;
        __syncthreads();
    }
    if (i < N_NODES) rowptr[i] = s[t] - v;
    if (t == 255) part[blockIdx.x] = s[t];
}

__global__ void k_scan2(int* __restrict__ part, int* __restrict__ rowptr, int* __restrict__ gstart) {
    __shared__ int s[512];
    int t = threadIdx.x;
    int v = (t < SCAN_BLOCKS) ? part[t] : 0;
    s[t] = v;
    __syncthreads();
    for (int off = 1; off < 512; off <<= 1) {
        int u = (t >= off) ? s[t - off] : 0;
        __syncthreads();
        s[t] += u;
        __syncthreads();
    }
    part[t] = s[t] - v;
    if (t == 0) rowptr[N_NODES] = EP;
    if (t <= NG) gstart[t] = N_NODES;   // fused init for graph bounds
}

// scan3 + cursor init + x packing (float3 -> bf16x4, 8B) + graph bounds, all fused
__global__ void k_scan3(const int* __restrict__ part, int* __restrict__ rowptr,
                        int* __restrict__ cursor, const float* __restrict__ x,
                        bf16_t* __restrict__ xb, const int* __restrict__ batch,
                        int* __restrict__ gstart) {
    int i = blockIdx.x * 256 + threadIdx.x;
    if (i < N_NODES) {
        int v = rowptr[i] + part[blockIdx.x];
        rowptr[i] = v;
        cursor[i] = v;
        ushort4 p;
        p.x = f2bf(x[i * 3 + 0]);
        p.y = f2bf(x[i * 3 + 1]);
        p.z = f2bf(x[i * 3 + 2]);
        p.w = 0;
        *(ushort4*)&xb[i * 4] = p;
        int b = batch[i];
        if (i == 0) {
            for (int g = 0; g <= b; g++) gstart[g] = 0;
        } else {
            int bp = batch[i - 1];
            if (b != bp)
                for (int g = bp + 1; g <= b; g++) gstart[g] = i;
        }
    }
}

__global__ void k_scatter(const int* __restrict__ ei, int* __restrict__ cursor, int* __restrict__ csr) {
    int i = blockIdx.x * 256 + threadIdx.x;
    if (i >= EP) return;
    int s, d;
    if (i < N_EDGES) { s = ei[i]; d = ei[N_EDGES + i]; }
    else { s = i - N_EDGES; d = s; }
    int pos = atomicAdd(&cursor[d], 1);
    csr[pos] = s;
}

// ---------------- layer 1: ONE wave per block (2 dsts, 32 lanes each; no block skew) ------
__global__ __launch_bounds__(64) void k_layer1(
    const bf16_t* __restrict__ xb, const int* __restrict__ rowptr, const int* __restrict__ csr,
    const float* __restrict__ W1, const float* __restrict__ wprep, const float* __restrict__ b1,
    bf16_t* __restrict__ x1p) {
    __shared__ float w1s[1536];
    __shared__ float wp[48];
    int lane = threadIdx.x;
    // vectorized LDS fill: 384 float4 by 64 lanes = 6 each
#pragma unroll
    for (int q = 0; q < 6; q++)
        *(float4*)&w1s[(q * 64 + lane) * 4] = *(const float4*)&W1[(q * 64 + lane) * 4];
    if (lane < 48) wp[lane] = wprep[lane];
    __syncthreads();
    int half = lane >> 5, l32 = lane & 31;
    int dst = blockIdx.x * 2 + half;
    int rs = rowptr[dst], re = rowptr[dst + 1];
    ushort4 xd4 = *(const ushort4*)&xb[dst * 4];
    float xdx = bf2f(xd4.x), xdy = bf2f(xd4.y), xdz = bf2f(xd4.z);
    float ald[NH];
#pragma unroll
    for (int h = 0; h < NH; h++)
        ald[h] = xdx * wp[24 + h * 3] + xdy * wp[24 + h * 3 + 1] + xdz * wp[24 + h * 3 + 2];
    float den[NH], c0[NH], c1[NH], c2[NH];
#pragma unroll
    for (int h = 0; h < NH; h++) { den[h] = 0.f; c0[h] = 0.f; c1[h] = 0.f; c2[h] = 0.f; }
    for (int base = rs; base < re; base += 32) {
        int e = base + l32;
        if (e < re) {
            int s = csr[e];
            ushort4 sv4 = *(const ushort4*)&xb[s * 4];
            float svx = bf2f(sv4.x), svy = bf2f(sv4.y), svz = bf2f(sv4.z);
#pragma unroll
            for (int h = 0; h < NH; h++) {
                float ev = svx * wp[h * 3] + svy * wp[h * 3 + 1] + svz * wp[h * 3 + 2] + ald[h];
                ev = fmaxf(ev, 0.2f * ev);
                float w = __expf(ev);
                den[h] += w;
                c0[h] += w * svx;
                c1[h] += w * svy;
                c2[h] += w * svz;
            }
        }
    }
#pragma unroll
    for (int h = 0; h < NH; h++) {
#pragma unroll
        for (int off = 1; off < 32; off <<= 1) {
            den[h] += __shfl_xor(den[h], off, 64);
            c0[h] += __shfl_xor(c0[h], off, 64);
            c1[h] += __shfl_xor(c1[h], off, 64);
            c2[h] += __shfl_xor(c2[h], off, 64);
        }
    }
    bf16_t vbA[NH], vbB[NH];
#pragma unroll
    for (int h = 0; h < NH; h++) {
        int colA = h * 64 + l32;
        float vA = c0[h] * w1s[colA] + c1[h] * w1s[512 + colA] + c2[h] * w1s[1024 + colA];
        vA = vA / den[h] + b1[colA];
        vA = vA > 0.f ? vA : (__expf(vA) - 1.f);
        vbA[h] = f2bf(vA);
        int colB = colA + 32;
        float vB = c0[h] * w1s[colB] + c1[h] * w1s[512 + colB] + c2[h] * w1s[1024 + colB];
        vB = vB / den[h] + b1[colB];
        vB = vB > 0.f ? vB : (__expf(vB) - 1.f);
        vbB[h] = f2bf(vB);
    }
    uint4 oA, oB;
    oA.x = (unsigned int)vbA[0] | ((unsigned int)vbA[1] << 16);
    oA.y = (unsigned int)vbA[2] | ((unsigned int)vbA[3] << 16);
    oA.z = (unsigned int)vbA[4] | ((unsigned int)vbA[5] << 16);
    oA.w = (unsigned int)vbA[6] | ((unsigned int)vbA[7] << 16);
    oB.x = (unsigned int)vbB[0] | ((unsigned int)vbB[1] << 16);
    oB.y = (unsigned int)vbB[2] | ((unsigned int)vbB[3] << 16);
    oB.z = (unsigned int)vbB[4] | ((unsigned int)vbB[5] << 16);
    oB.w = (unsigned int)vbB[6] | ((unsigned int)vbB[7] << 16);
    *(uint4*)&x1p[(size_t)dst * HC + l32 * 8] = oA;
    *(uint4*)&x1p[(size_t)dst * HC + (l32 + 32) * 8] = oB;
}

// ---------------- GEMM2 128x128, BK=64, async staging; h2 OUTPUT IN FP8-e4m3 ----------------
__global__ __launch_bounds__(256) void k_gemm2(const bf16_t* __restrict__ A,
                                               const bf16_t* __restrict__ BT,
                                               fp8_t* __restrict__ Out,
                                               int row_base, int nrows,
                                               const float* __restrict__ a2s,
                                               const float* __restrict__ a2d,
                                               float* __restrict__ al2s,
                                               float* __restrict__ al2d) {
    __shared__ short smem[16384];          // As 8192 | Bs 8192 (128 rows x 64 shorts each)
    short* As = smem;
    short* Bs = smem + 8192;
    int tid = threadIdx.x;
    int lane = tid & 63, wave = tid >> 6;
    int wm = wave & 1, wn = wave >> 1;
    int lm = lane & 15, quad = lane >> 4;
    int gx = blockIdx.x, gy = blockIdx.y;
    int l8 = lane >> 3, lc8 = lane & 7;
    int sw = lc8 ^ l8;                     // swizzled global chunk for this lane
    const bf16_t* ga[4];
    const bf16_t* gb[4];
    short* la[4];
    short* lb[4];
#pragma unroll
    for (int it = 0; it < 4; it++) {
        int ar = gy * 128 + wave * 32 + it * 8 + l8;
        int arc = (ar < nrows) ? ar : 0;   // clamp OOB (rows never stored)
        ga[it] = A + (size_t)(row_base + arc) * HC + sw * 8;
        gb[it] = BT + (size_t)(gx * 128 + wave * 32 + it * 8 + l8) * HC + sw * 8;
        la[it] = As + (wave * 32 + it * 8) * 64;
        lb[it] = Bs + (wave * 32 + it * 8) * 64;
    }

    floatx4 acc[4][4];
#pragma unroll
    for (int mi = 0; mi < 4; mi++)
#pragma unroll
        for (int ni = 0; ni < 4; ni++) acc[mi][ni] = (floatx4){0.f, 0.f, 0.f, 0.f};

    int lmw = lm & 7;  // read-side swizzle key (row & 7)
    for (int k0 = 0; k0 < HC; k0 += 64) {
        __syncthreads();
#pragma unroll
        for (int it = 0; it < 4; it++) ldsload16(ga[it] + k0, la[it]);
#pragma unroll
        for (int it = 0; it < 4; it++) ldsload16(gb[it] + k0, lb[it]);
        __syncthreads();
        short8 af[4][2], bf[4][2];
#pragma unroll
        for (int mi = 0; mi < 4; mi++)
#pragma unroll
            for (int kk = 0; kk < 2; kk++) {
                int pos = (kk * 4 + quad) ^ lmw;
                af[mi][kk] = *(const short8*)&As[(wm * 64 + mi * 16 + lm) * 64 + pos * 8];
            }
#pragma unroll
        for (int ni = 0; ni < 4; ni++)
#pragma unroll
            for (int kk = 0; kk < 2; kk++) {
                int pos = (kk * 4 + quad) ^ lmw;
                bf[ni][kk] = *(const short8*)&Bs[(wn * 64 + ni * 16 + lm) * 64 + pos * 8];
            }
#pragma unroll
        for (int mi = 0; mi < 4; mi++)
#pragma unroll
            for (int ni = 0; ni < 4; ni++) {
                acc[mi][ni] = __builtin_amdgcn_mfma_f32_16x16x32_bf16(af[mi][0], bf[ni][0], acc[mi][ni], 0, 0, 0);
                acc[mi][ni] = __builtin_amdgcn_mfma_f32_16x16x32_bf16(af[mi][1], bf[ni][1], acc[mi][ni], 0, 0, 0);
            }
    }
    // ---- fused al2 from fp32 acc (EXACT logits; unaffected by fp8 h2 storage) ----
    int head = gx * 2 + wn;
    float a2sv[4], a2dv[4];
#pragma unroll
    for (int ni = 0; ni < 4; ni++) {
        int col = gx * 128 + wn * 64 + ni * 16 + lm;
        a2sv[ni] = a2s[col];
        a2dv[ni] = a2d[col];
    }
#pragma unroll
    for (int mi = 0; mi < 4; mi++) {
#pragma unroll
        for (int rg = 0; rg < 4; rg++) {
            int lrow = gy * 128 + wm * 64 + mi * 16 + quad * 4 + rg;
            float ps = 0.f, pd = 0.f;
#pragma unroll
            for (int ni = 0; ni < 4; ni++) {
                float v = acc[mi][ni][rg];
                ps += v * a2sv[ni];
                pd += v * a2dv[ni];
            }
#pragma unroll
            for (int off = 1; off < 16; off <<= 1) {
                ps += __shfl_xor(ps, off, 64);
                pd += __shfl_xor(pd, off, 64);
            }
            if (lrow < nrows && lm == 0) {
                int ar = row_base + lrow;
                al2s[ar * NH + head] = ps;
                al2d[ar * NH + head] = pd;
            }
        }
    }
    // ---- fp8 store via per-wave LDS byte patch (uint4 global stores, 64B/row segments) ----
    __syncthreads();
    unsigned char* bpatch = (unsigned char*)smem + wave * (32 * BPSTR);
#pragma unroll
    for (int p = 0; p < 2; p++) {
#pragma unroll
        for (int mih = 0; mih < 2; mih++) {
            int mi = p * 2 + mih;
#pragma unroll
            for (int ni = 0; ni < 4; ni++)
#pragma unroll
                for (int rg = 0; rg < 4; rg++) {
                    int rl = mih * 16 + quad * 4 + rg;
                    bpatch[rl * BPSTR + ni * 16 + lm] = f2fp8(acc[mi][ni][rg]);
                }
        }
        // same-wave LDS write->read in program order
#pragma unroll
        for (int it = 0; it < 2; it++) {
            int idx = it * 64 + lane;
            int rl = idx >> 2, c16 = idx & 3;
            uint4 v = *(uint4*)&bpatch[rl * BPSTR + c16 * 16];
            int lrow = gy * 128 + wm * 64 + p * 32 + rl;
            if (lrow < nrows)
                *(uint4*)&Out[(size_t)lrow * HC + wn * 64 + gx * 128 + c16 * 16] = v;
        }
        __syncthreads();
    }
}

// ---------------- layer 2: ONE dst per 64-thread block (no intra-block skew), x4 unroll ----
__global__ __launch_bounds__(64) void k_layer2pool(
    const fp8_t* __restrict__ h2lo, const fp8_t* __restrict__ h2hi, int srows,
    const float* __restrict__ al2s, const float* __restrict__ al2d,
    const int* __restrict__ rowptr, const int* __restrict__ csr, const float* __restrict__ b2,
    const int* __restrict__ batch, float* __restrict__ poolpart) {
    __shared__ float wlds[512];
    __shared__ int slds[64];
    int lane = threadIdx.x;
    int hme = lane >> 3;
    int dst = blockIdx.x;
    int rs = rowptr[dst], re = rowptr[dst + 1];
    float4 d0 = *(const float4*)&al2d[dst * NH];
    float4 d1 = *(const float4*)&al2d[dst * NH + 4];
    float ald[NH] = {d0.x, d0.y, d0.z, d0.w, d1.x, d1.y, d1.z, d1.w};
    float den[NH], acc[8];
#pragma unroll
    for (int h = 0; h < NH; h++) den[h] = 0.f;
#pragma unroll
    for (int q = 0; q < 8; q++) acc[q] = 0.f;
    for (int base = rs; base < re; base += 64) {
        int e = base + lane;
        int cl = re - base; if (cl > 64) cl = 64;
        float w[NH];
        int s = 0;
        if (e < re) {
            s = csr[e];
            float4 p0 = *(const float4*)&al2s[s * NH];
            float4 p1 = *(const float4*)&al2s[s * NH + 4];
            float als[NH] = {p0.x, p0.y, p0.z, p0.w, p1.x, p1.y, p1.z, p1.w};
#pragma unroll
            for (int h = 0; h < NH; h++) {
                float ev = als[h] + ald[h];
                ev = fmaxf(ev, 0.2f * ev);
                w[h] = __expf(ev);
                den[h] += w[h];
            }
        } else {
#pragma unroll
            for (int h = 0; h < NH; h++) w[h] = 0.f;
        }
        slds[lane] = s;
        *(float4*)&wlds[lane * 8] = make_float4(w[0], w[1], w[2], w[3]);
        *(float4*)&wlds[lane * 8 + 4] = make_float4(w[4], w[5], w[6], w[7]);
        // same-wave LDS write->read in program order; x4 unroll = 4 gathers in flight
        int j = 0;
        for (; j + 3 < cl; j += 4) {
            int s0 = slds[j + 0], s1 = slds[j + 1];
            int s2 = slds[j + 2], s3 = slds[j + 3];
            float w0 = wlds[(j + 0) * 8 + hme];
            float w1 = wlds[(j + 1) * 8 + hme];
            float w2 = wlds[(j + 2) * 8 + hme];
            float w3 = wlds[(j + 3) * 8 + hme];
            const fp8_t* b0 = (s0 < srows) ? (h2lo + (size_t)s0 * HC) : (h2hi + (size_t)(s0 - srows) * HC);
            const fp8_t* b1p = (s1 < srows) ? (h2lo + (size_t)s1 * HC) : (h2hi + (size_t)(s1 - srows) * HC);
            const fp8_t* b2p = (s2 < srows) ? (h2lo + (size_t)s2 * HC) : (h2hi + (size_t)(s2 - srows) * HC);
            const fp8_t* b3p = (s3 < srows) ? (h2lo + (size_t)s3 * HC) : (h2hi + (size_t)(s3 - srows) * HC);
            uint2 v0 = *(const uint2*)&b0[lane * 8];
            uint2 v1 = *(const uint2*)&b1p[lane * 8];
            uint2 v2 = *(const uint2*)&b2p[lane * 8];
            uint2 v3 = *(const uint2*)&b3p[lane * 8];
            floatx2 c;
            c = __builtin_amdgcn_cvt_pk_f32_fp8(v0.x, false); acc[0] += w0 * c.x; acc[1] += w0 * c.y;
            c = __builtin_amdgcn_cvt_pk_f32_fp8(v0.x, true);  acc[2] += w0 * c.x; acc[3] += w0 * c.y;
            c = __builtin_amdgcn_cvt_pk_f32_fp8(v0.y, false); acc[4] += w0 * c.x; acc[5] += w0 * c.y;
            c = __builtin_amdgcn_cvt_pk_f32_fp8(v0.y, true);  acc[6] += w0 * c.x; acc[7] += w0 * c.y;
            c = __builtin_amdgcn_cvt_pk_f32_fp8(v1.x, false); acc[0] += w1 * c.x; acc[1] += w1 * c.y;
            c = __builtin_amdgcn_cvt_pk_f32_fp8(v1.x, true);  acc[2] += w1 * c.x; acc[3] += w1 * c.y;
            c = __builtin_amdgcn_cvt_pk_f32_fp8(v1.y, false); acc[4] += w1 * c.x; acc[5] += w1 * c.y;
            c = __builtin_amdgcn_cvt_pk_f32_fp8(v1.y, true);  acc[6] += w1 * c.x; acc[7] += w1 * c.y;
            c = __builtin_amdgcn_cvt_pk_f32_fp8(v2.x, false); acc[0] += w2 * c.x; acc[1] += w2 * c.y;
            c = __builtin_amdgcn_cvt_pk_f32_fp8(v2.x, true);  acc[2] += w2 * c.x; acc[3] += w2 * c.y;
            c = __builtin_amdgcn_cvt_pk_f32_fp8(v2.y, false); acc[4] += w2 * c.x; acc[5] += w2 * c.y;
            c = __builtin_amdgcn_cvt_pk_f32_fp8(v2.y, true);  acc[6] += w2 * c.x; acc[7] += w2 * c.y;
            c = __builtin_amdgcn_cvt_pk_f32_fp8(v3.x, false); acc[0] += w3 * c.x; acc[1] += w3 * c.y;
            c = __builtin_amdgcn_cvt_pk_f32_fp8(v3.x, true);  acc[2] += w3 * c.x; acc[3] += w3 * c.y;
            c = __builtin_amdgcn_cvt_pk_f32_fp8(v3.y, false); acc[4] += w3 * c.x; acc[5] += w3 * c.y;
            c = __builtin_amdgcn_cvt_pk_f32_fp8(v3.y, true);  acc[6] += w3 * c.x; acc[7] += w3 * c.y;
        }
        for (; j < cl; j++) {
            int sA = slds[j];
            float wA = wlds[j * 8 + hme];
            const fp8_t* bA = (sA < srows) ? (h2lo + (size_t)sA * HC) : (h2hi + (size_t)(sA - srows) * HC);
            uint2 vA = *(const uint2*)&bA[lane * 8];
            floatx2 c;
            c = __builtin_amdgcn_cvt_pk_f32_fp8(vA.x, false); acc[0] += wA * c.x; acc[1] += wA * c.y;
            c = __builtin_amdgcn_cvt_pk_f32_fp8(vA.x, true);  acc[2] += wA * c.x; acc[3] += wA * c.y;
            c = __builtin_amdgcn_cvt_pk_f32_fp8(vA.y, false); acc[4] += wA * c.x; acc[5] += wA * c.y;
            c = __builtin_amdgcn_cvt_pk_f32_fp8(vA.y, true);  acc[6] += wA * c.x; acc[7] += wA * c.y;
        }
    }
#pragma unroll
    for (int h = 0; h < NH; h++)
#pragma unroll
        for (int off = 1; off < 64; off <<= 1) den[h] += __shfl_xor(den[h], off, 64);
    float dd = den[0];
#pragma unroll
    for (int h = 1; h < NH; h++) dd = (hme == h) ? den[h] : dd;
    float dinv = 1.0f / dd;
    float4 ba = *(const float4*)&b2[lane * 8];
    float4 bb = *(const float4*)&b2[lane * 8 + 4];
    float bv[8] = {ba.x, ba.y, ba.z, ba.w, bb.x, bb.y, bb.z, bb.w};
    // stage post-ELU values in LDS, then atomics in COALESCED (h*64+lane) order
#pragma unroll
    for (int q = 0; q < 8; q++) {
        float v = acc[q] * dinv + bv[q];
        v = v > 0.f ? v : (__expf(v) - 1.f);
        wlds[lane * 8 + q] = v;
    }
    int g = batch[dst];
    float* pp = poolpart + ((size_t)(blockIdx.x & (NPART - 1)) * NG + g) * HC;
#pragma unroll
    for (int h = 0; h < NH; h++)
        atomicAdd(&pp[h * 64 + lane], wlds[h * 64 + lane]);
}

// ---------------- fused pool-reduce + classifier ----------------
__global__ __launch_bounds__(256) void k_poolcls(const float* __restrict__ poolpart,
                                                 const int* __restrict__ gstart,
                                                 const float* __restrict__ Wc,
                                                 const float* __restrict__ bc,
                                                 float* __restrict__ out) {
    __shared__ float pl[512];
    int g = blockIdx.x, t = threadIdx.x;
    for (int c = t; c < HC; c += 256) {
        float s = 0.f;
        for (int p = 0; p < NPART; p++) s += poolpart[(size_t)p * NG * HC + g * HC + c];
        pl[c] = s;
    }
    __syncthreads();
    if (t < 10) {
        float cnt = fmaxf((float)(gstart[g + 1] - gstart[g]), 1.0f);
        float acc = 0.f;
        for (int k = 0; k < HC; k++) acc += pl[k] * Wc[k * 10 + t];
        out[g * 10 + t] = acc / cnt + bc[t];
    }
}

extern "C" void kernel_launch(void* const* d_in, const int* in_sizes, int n_in,
                              void* d_out, int out_size, void* d_ws, size_t ws_size,
                              hipStream_t stream) {
    const float* x   = (const float*)d_in[0];
    const int*   ei  = (const int*)d_in[1];
    const int*   bat = (const int*)d_in[2];
    const float* W1  = (const float*)d_in[3];
    const float* a1s = (const float*)d_in[4];
    const float* a1d = (const float*)d_in[5];
    const float* b1  = (const float*)d_in[6];
    const float* W2  = (const float*)d_in[7];
    const float* a2s = (const float*)d_in[8];
    const float* a2d = (const float*)d_in[9];
    const float* b2  = (const float*)d_in[10];
    const float* Wc  = (const float*)d_in[11];
    const float* bc  = (const float*)d_in[12];
    float* out = (float*)d_out;

    char* ws = (char*)d_ws;
    size_t off = 0;
    auto alloc = [&](size_t bytes) {
        size_t o = off;
        off += (bytes + 255) & ~(size_t)255;
        return o;
    };
    float*  wprep    = (float*)(ws + alloc(48 * 4));
    int*    rowptr   = (int*)(ws + alloc((size_t)(N_NODES + 1) * 4));
    int*    deg      = (int*)(ws + alloc((size_t)N_NODES * 4));
    int*    cursor   = (int*)(ws + alloc((size_t)N_NODES * 4));
    int*    part     = (int*)(ws + alloc(512 * 4));
    int*    gstart   = (int*)(ws + alloc(65 * 4));
    bf16_t* xb       = (bf16_t*)(ws + alloc((size_t)N_NODES * 4 * 2));
    int*    csr      = (int*)(ws + alloc((size_t)EP * 4));
    bf16_t* x1b      = (bf16_t*)(ws + alloc((size_t)N_NODES * HC * 2));
    float*  al2s     = (float*)(ws + alloc((size_t)N_NODES * NH * 4));
    float*  al2d     = (float*)(ws + alloc((size_t)N_NODES * NH * 4));
    float*  poolpart = (float*)(ws + alloc((size_t)NPART * NG * HC * 4));
    // W2T (512KB) aliases deg+cursor (800KB, dead after k_scatter)
    bf16_t* W2T = (bf16_t*)deg;

    // slice tier: h2 is FP8 (1 byte/elem) — largest slice temp that fits
    size_t rem = (ws_size > off) ? ws_size - off : 0;
    int nslices, srows;
    if (rem >= (size_t)N_NODES * HC)      { nslices = 1;  srows = N_NODES; }
    else if (rem >= (size_t)50000 * HC)   { nslices = 2;  srows = 50000; }
    else if (rem >= (size_t)25000 * HC)   { nslices = 4;  srows = 25000; }
    else if (rem >= (size_t)12500 * HC)   { nslices = 8;  srows = 12500; }
    else                                  { nslices = 16; srows = 6250; }
    fp8_t* T = (fp8_t*)(ws + alloc((size_t)srows * HC));
    fp8_t* h2hi = (fp8_t*)x1b;   // shift-by-one in-place region (byte-indexed)

    hipMemsetAsync(deg, 0, (size_t)N_NODES * 4, stream);
    hipMemsetAsync(poolpart, 0, (size_t)NPART * NG * HC * 4, stream);

    k_deg<<<(EP + 255) / 256, 256, 0, stream>>>(ei, deg);
    k_scan1<<<SCAN_BLOCKS, 256, 0, stream>>>(deg, rowptr, part);
    k_scan2<<<1, 512, 0, stream>>>(part, rowptr, gstart);
    k_scan3<<<SCAN_BLOCKS, 256, 0, stream>>>(part, rowptr, cursor, x, xb, bat, gstart);
    k_scatter<<<(EP + 255) / 256, 256, 0, stream>>>(ei, cursor, csr);
    k_prepw2t<<<NBW2T + 1, 256, 0, stream>>>(W1, a1s, a1d, wprep, W2, W2T);
    k_layer1<<<N_NODES / 2, 64, 0, stream>>>(xb, rowptr, csr, W1, wprep, b1, x1b);
    // shift-by-one in-place GEMM (fp8 out): slice 0 -> T; slice i -> bytes of consumed x1 rows.
    for (int s = 0; s < nslices; s++) {
        fp8_t* outp = (s == 0) ? T : (h2hi + (size_t)(s - 1) * srows * HC);
        k_gemm2<<<dim3(4, (srows + 127) / 128), 256, 0, stream>>>(
            x1b, W2T, outp, s * srows, srows, a2s, a2d, al2s, al2d);
    }
    k_layer2pool<<<N_NODES, 64, 0, stream>>>(T, h2hi, srows, al2s, al2d,
                                             rowptr, csr, b2, bat, poolpart);
    k_poolcls<<<NG, 256, 0, stream>>>(poolpart, gstart, Wc, bc, out);
}